// Round 8
// baseline (12939.040 us; speedup 1.0000x reference)
//
#include <hip/hip_runtime.h>
#include <math.h>

#define BEAM   10
#define MAXLEN 32
#define SLEN   32
#define HD     500
#define ED     500
#define G4     2000
#define PV     50000
#define NEGF   (-1e30f)
#define NEGD   (-1.0e30)

#define GRID2  256          // mega grid: 256 blocks x 256 thr = always co-resident on 256-CU gfx950
#define NW     1024         // GRID2*4 waves
#define STRIP  196          // cols per block in logits phase (256*196 >= 50000)

typedef unsigned long long u64;

// ---------------- ws layout (float element offsets) ----------------
#define OFF_X      0
#define OFF_CBUF   64000
#define OFF_GBUF   65000
#define OFF_CTX    69000
#define OFF_DH     85000
#define OFF_DC     90000
#define OFF_DG     95000
#define OFF_H2     115000
#define OFF_C2     120000
#define OFF_O      125000
#define OFF_SCD    135000
#define OFF_TOK    135020
#define OFF_PREVK  135040
#define OFF_NEXTY  135360
// fallback-path regions (R4 layout)
#define OFF_PARTF  136000   // double[7820]
#define OFF_CANDF  152000   // u64[3200]
#define OFF_LOG    160000   // only used by fallback kernels
// mega-path regions (live inside the fallback LOG region; paths are exclusive)
#define OFF_BAR    160000   // int[264]: [0..255] flags, [256] done
#define OFF_LSE    160264   // double[10]
#define OFF_PARTD  160284   // double[10*256]
#define OFF_RC     165404   // u64[100]
#define OFF_CAND   165604   // u64[10*2560]
#define OFF_OWT    660000   // float4-blocked transposed out_W (100 MB)
#define NEED_T_BYTES ((size_t)(OFF_OWT + (size_t)HD * PV) * 4)

__device__ __forceinline__ float sigf(float x) { return 1.f / (1.f + expf(-x)); }

__device__ __forceinline__ unsigned fkey(float f) {
    unsigned u = __float_as_uint(f);
    return (u & 0x80000000u) ? ~u : (u | 0x80000000u);
}
__device__ __forceinline__ float unfkey(unsigned k) {
    unsigned u = (k & 0x80000000u) ? (k & 0x7fffffffu) : ~k;
    return __uint_as_float(u);
}

// Contention-free grid barrier: per-block flag array + generation counter.
// Arrivals are 256 PARALLEL release-stores (distinct words); wave 0 of each
// block polls all 256 flags with 4 lane-parallel acquire loads per iteration.
// All GRID2 blocks are co-resident (1 block/CU), so spinning is deadlock-free.
__device__ __forceinline__ void gbar2(int* flags, int gen) {
    __syncthreads();
    if (threadIdx.x == 0)
        __hip_atomic_store(&flags[blockIdx.x], gen, __ATOMIC_RELEASE, __HIP_MEMORY_SCOPE_AGENT);
    if (threadIdx.x < 64) {
        int l = threadIdx.x;
        for (;;) {
            int v0 = __hip_atomic_load(&flags[l],       __ATOMIC_ACQUIRE, __HIP_MEMORY_SCOPE_AGENT);
            int v1 = __hip_atomic_load(&flags[l + 64],  __ATOMIC_ACQUIRE, __HIP_MEMORY_SCOPE_AGENT);
            int v2 = __hip_atomic_load(&flags[l + 128], __ATOMIC_ACQUIRE, __HIP_MEMORY_SCOPE_AGENT);
            int v3 = __hip_atomic_load(&flags[l + 192], __ATOMIC_ACQUIRE, __HIP_MEMORY_SCOPE_AGENT);
            bool ok = (v0 >= gen) && (v1 >= gen) && (v2 >= gen) && (v3 >= gen);
            if (__all(ok)) break;
            __builtin_amdgcn_s_sleep(2);
        }
    }
    __syncthreads();
}

// ---------------- prep (also resets barrier state every call/replay) ----------------
__global__ void k_prep(const int* __restrict__ g_seq, const float* __restrict__ enc_emb,
                       const float* __restrict__ Wih, const float* __restrict__ bih,
                       const float* __restrict__ bhh, float* __restrict__ X,
                       float* __restrict__ cbuf0, int* __restrict__ bar) {
    if (blockIdx.x == 0) {
        for (int j = threadIdx.x; j < HD; j += 256) cbuf0[j] = 0.f;
        for (int j = threadIdx.x; j < 264; j += 256) bar[j] = 0;
    }
    int wv = (blockIdx.x * blockDim.x + threadIdx.x) >> 6;
    int lane = threadIdx.x & 63;
    if (wv >= SLEN * G4) return;
    int t = wv / G4, r = wv - t * G4;
    const float* emb = enc_emb + (size_t)g_seq[t] * ED;
    const float* w = Wih + (size_t)r * ED;
    float acc = 0.f;
    for (int ki = 0; ki < 8; ki++) { int k = ki * 64 + lane; if (k < ED) acc += emb[k] * w[k]; }
    for (int o = 32; o; o >>= 1) acc += __shfl_down(acc, o);
    if (lane == 0) X[t * G4 + r] = acc + bih[r] + bhh[r];
}

// ---------------- out_W blocked transpose ----------------
__global__ void k_transpose4(const float* __restrict__ outW, float* __restrict__ outW4) {
    __shared__ float t_lds[64][65];
    int tid = threadIdx.x;
    int pbase = blockIdx.x * 64, kbase = blockIdx.y * 64;
    for (int e = 0; e < 16; e++) {
        int idx = e * 256 + tid; int pl = idx >> 6, kl = idx & 63;
        int pp = pbase + pl, kk = kbase + kl;
        t_lds[pl][kl] = (pp < PV && kk < HD) ? outW[(size_t)pp * HD + kk] : 0.f;
    }
    __syncthreads();
    for (int e = 0; e < 4; e++) {
        int idx = e * 256 + tid;
        int pl = idx & 63, kb = idx >> 6;
        int pp = pbase + pl;
        int kglob = kbase + kb * 4;
        if (pp < PV && kglob < HD) {
            float4 v;
            v.x = t_lds[pl][kb * 4 + 0];
            v.y = t_lds[pl][kb * 4 + 1];
            v.z = t_lds[pl][kb * 4 + 2];
            v.w = t_lds[pl][kb * 4 + 3];
            *(float4*)(outW4 + ((size_t)(kbase / 4 + kb) * PV + pp) * 4) = v;
        }
    }
}

// ================= mega args =================
struct MegaA {
    const float* encWhh; const float* X;
    float* gbuf; float* cbuf; float* ctx;
    const float* decEmb; const float* decWih; const float* decWhh;
    const float* decBih; const float* decBhh; const float* attnW;
    const float* outW4; const float* outB;
    float* dh; float* dc; float* dg; float* h2w; float* c2w; float* ow;
    double* sc; double* part; double* lse;
    int* tok; int* prevK; int* nextY; u64* cand; u64* rc; int* outTok;
    int* bar;   // [0..255] flags, [256] done
};

struct MS {
    double scl[BEAM]; double lse2[BEAM];
    double bwv[4]; unsigned bwf[4]; unsigned winf;
    int pk[BEAM]; int ny[BEAM]; double val[BEAM];
};

// ================= persistent mega (normal launch, flag-array barrier) =================
__global__ __launch_bounds__(256) void k_mega2(MegaA A) {
    __shared__ __align__(16) char smem_raw[44032];
    float* smf = (float*)smem_raw;
    int* flags = A.bar;
    int* done  = A.bar + 256;
    int gen = 0;
    const int tid = threadIdx.x, bid = blockIdx.x;
    const int wv = tid >> 6, lane = tid & 63;
    const int gw = bid * 4 + wv;

    // ===== encoder: 33 steps =====
    for (int t = 0; t <= SLEN; ++t) {
        const float* gprev = A.gbuf + ((t + 1) & 1) * G4;
        float*       gcur  = A.gbuf + (t & 1) * G4;
        const float* cprev = A.cbuf + ((t + 1) & 1) * HD;
        float*       ccur  = A.cbuf + (t & 1) * HD;
        if (t < SLEN || bid == 0) {
            float* h_lds = smf;
            if (t > 0) {
                for (int j = tid; j < HD; j += 256) {
                    float gi = gprev[j], gf = gprev[HD + j], gg = gprev[2 * HD + j], go = gprev[3 * HD + j];
                    float c = sigf(gf) * cprev[j] + sigf(gi) * tanhf(gg);
                    float h = sigf(go) * tanhf(c);
                    h_lds[j] = h;
                    if (bid == 0) {
                        ccur[j] = c;
                        A.ctx[(t - 1) * HD + j] = h;
                        if (t == SLEN) {
                            for (int b = 0; b < BEAM; b++) { A.dh[b * HD + j] = h; A.dc[b * HD + j] = c; }
                        }
                    }
                }
            } else {
                for (int j = tid; j < HD; j += 256) h_lds[j] = 0.f;
            }
            if (t == SLEN && bid == 0 && tid == 0) {
                for (int b = 0; b < BEAM; b++) A.sc[b] = 0.0;
                A.tok[0] = 2; for (int b = 1; b < BEAM; b++) A.tok[b] = 1;
            }
            __syncthreads();
            if (t < SLEN) {
                for (int r = gw; r < G4; r += NW) {
                    const float* w = A.encWhh + (size_t)r * HD;
                    float acc = 0.f;
                    for (int ki = 0; ki < 8; ki++) { int k = ki * 64 + lane; if (k < HD) acc += h_lds[k] * w[k]; }
                    for (int o = 32; o; o >>= 1) acc += __shfl_down(acc, o);
                    if (lane == 0) gcur[r] = A.X[t * G4 + r] + acc;
                }
            }
        }
        gbar2(flags, ++gen);
    }

    // ===== decode: 32 steps x 4 barriers =====
    for (int t = 0; t < MAXLEN; ++t) {
        // ---- phase G: gates (all 256 blocks, rows strided) ----
        {
            float* e_lds = smf;               // 5000
            float* h_lds = smf + 5000;        // 5000
            for (int idx = tid; idx < BEAM * ED; idx += 256) {
                int b = idx / ED, k = idx - b * ED;
                e_lds[idx] = A.decEmb[(size_t)A.tok[b] * ED + k];
                h_lds[idx] = A.dh[idx];
            }
            __syncthreads();
            for (int r = gw; r < G4; r += NW) {
                const float* wi = A.decWih + (size_t)r * ED;
                const float* wh = A.decWhh + (size_t)r * HD;
                float acc[BEAM];
#pragma unroll
                for (int b = 0; b < BEAM; b++) acc[b] = 0.f;
                for (int ki = 0; ki < 8; ki++) {
                    int k = ki * 64 + lane;
                    if (k < ED) {
                        float w = wi[k];
#pragma unroll
                        for (int b = 0; b < BEAM; b++) acc[b] += w * e_lds[b * ED + k];
                    }
                }
                for (int ki = 0; ki < 8; ki++) {
                    int k = ki * 64 + lane;
                    if (k < HD) {
                        float w = wh[k];
#pragma unroll
                        for (int b = 0; b < BEAM; b++) acc[b] += w * h_lds[b * HD + k];
                    }
                }
#pragma unroll
                for (int b = 0; b < BEAM; b++) {
                    float v = acc[b];
                    for (int o = 32; o; o >>= 1) v += __shfl_down(v, o);
                    acc[b] = v;
                }
                if (lane == 0) {
                    float bb = A.decBih[r] + A.decBhh[r];
#pragma unroll
                    for (int b = 0; b < BEAM; b++) A.dg[b * G4 + r] = acc[b] + bb;
                }
            }
        }
        gbar2(flags, ++gen);

        // ---- phase A: LSTM pointwise + attention + oproj (blocks 0..124) ----
        if (bid < 125) {
            float* h2_lds   = smf;
            float* wctx_lds = smf + 5000;
            float* s_lds    = smf + 10000;
            float* a_lds    = smf + 10320;
            for (int idx = tid; idx < BEAM * HD; idx += 256) {
                int b = idx / HD, j = idx - b * HD;
                float gi = A.dg[b * G4 + j], gf = A.dg[b * G4 + HD + j];
                float gg = A.dg[b * G4 + 2 * HD + j], go = A.dg[b * G4 + 3 * HD + j];
                float c = sigf(gf) * A.dc[idx] + sigf(gi) * tanhf(gg);
                float h2 = sigf(go) * tanhf(c);
                h2_lds[idx] = h2;
                if (bid == 0) { A.c2w[idx] = c; A.h2w[idx] = h2; }
            }
            __syncthreads();
            for (int si = 0; si < 8; ++si) {
                int s = wv + 4 * si;
                float acc[BEAM];
#pragma unroll
                for (int b = 0; b < BEAM; b++) acc[b] = 0.f;
                for (int ki = 0; ki < 8; ki++) {
                    int k = ki * 64 + lane;
                    if (k < HD) {
                        float c = A.ctx[s * HD + k];
#pragma unroll
                        for (int b = 0; b < BEAM; b++) acc[b] += c * h2_lds[b * HD + k];
                    }
                }
#pragma unroll
                for (int b = 0; b < BEAM; b++) {
                    float v = acc[b];
                    for (int o = 32; o; o >>= 1) v += __shfl_down(v, o);
                    if (lane == 0) s_lds[b * SLEN + s] = v;
                }
            }
            __syncthreads();
            if (wv == 0) {
                for (int b = 0; b < BEAM; ++b) {
                    float v = (lane < SLEN) ? s_lds[b * SLEN + lane] : -INFINITY;
                    float m = v;
                    for (int o = 32; o; o >>= 1) m = fmaxf(m, __shfl_xor(m, o));
                    float e = (lane < SLEN) ? expf(v - m) : 0.f;
                    float sum = e;
                    for (int o = 32; o; o >>= 1) sum += __shfl_xor(sum, o);
                    if (lane < SLEN) a_lds[b * SLEN + lane] = e / sum;
                }
            }
            __syncthreads();
            {
                float w0[BEAM], w1[BEAM];
#pragma unroll
                for (int b = 0; b < BEAM; b++) { w0[b] = 0.f; w1[b] = 0.f; }
                int j0 = tid, j1 = tid + 256;
                for (int s = 0; s < SLEN; ++s) {
                    float c0 = (j0 < HD) ? A.ctx[s * HD + j0] : 0.f;
                    float c1 = (j1 < HD) ? A.ctx[s * HD + j1] : 0.f;
#pragma unroll
                    for (int b = 0; b < BEAM; b++) {
                        float a = a_lds[b * SLEN + s];
                        w0[b] += a * c0; w1[b] += a * c1;
                    }
                }
#pragma unroll
                for (int b = 0; b < BEAM; b++) {
                    if (j0 < HD) wctx_lds[b * HD + j0] = w0[b];
                    if (j1 < HD) wctx_lds[b * HD + j1] = w1[b];
                }
            }
            __syncthreads();
            int j = gw;
            const float* w = A.attnW + (size_t)j * 1000;
            float acc[BEAM];
#pragma unroll
            for (int b = 0; b < BEAM; b++) acc[b] = 0.f;
            for (int ki = 0; ki < 16; ki++) {
                int k = ki * 64 + lane;
                if (k < 1000) {
                    float wk = w[k];
#pragma unroll
                    for (int b = 0; b < BEAM; b++) {
                        float h = (k < HD) ? h2_lds[b * HD + k] : wctx_lds[b * HD + k - HD];
                        acc[b] += wk * h;
                    }
                }
            }
#pragma unroll
            for (int b = 0; b < BEAM; b++) {
                float v = acc[b];
                for (int o = 32; o; o >>= 1) v += __shfl_down(v, o);
                acc[b] = v;
            }
            if (lane == 0) {
#pragma unroll
                for (int b = 0; b < BEAM; b++) A.ow[b * HD + j] = tanhf(acc[b]);
            }
        }
        gbar2(flags, ++gen);

        // ---- phase L+T: logits (1 col/thread) + per-strip top-10 + fp64 partial sumexp ----
        {
            float4* o4 = (float4*)smem_raw;   // 1250 float4 = 20000 B
            for (int idx = tid; idx < BEAM * 125; idx += 256) {
                int b = idx / 125, kb = idx - b * 125;
                o4[idx] = *(const float4*)(A.ow + b * HD + kb * 4);
            }
            __syncthreads();
            int p = bid * STRIP + tid;
            bool valid = (tid < STRIP) && (p < PV);
            int pc = (p < PV) ? p : (PV - 1);
            float lg[BEAM];
            {
                float acc[BEAM];
#pragma unroll
                for (int b = 0; b < BEAM; b++) acc[b] = 0.f;
                const float4* wp = (const float4*)A.outW4;
                for (int kb = 0; kb < 125; ++kb) {
                    float4 w = wp[(size_t)kb * PV + pc];
#pragma unroll
                    for (int b = 0; b < BEAM; b++) {
                        float4 o = o4[b * 125 + kb];
                        acc[b] += w.x * o.x + w.y * o.y + w.z * o.z + w.w * o.w;
                    }
                }
                float ob = A.outB[pc];
#pragma unroll
                for (int b = 0; b < BEAM; b++) lg[b] = acc[b] + ob;
            }
            // fp64 partial sumexp per row
            double* pd = (double*)(smem_raw + 20480);
#pragma unroll
            for (int b = 0; b < BEAM; b++) pd[b * 256 + tid] = valid ? exp((double)lg[b]) : 0.0;
            __syncthreads();
            for (int r = wv; r < BEAM; r += 4) {
                double s = pd[r * 256 + lane] + pd[r * 256 + 64 + lane]
                         + pd[r * 256 + 128 + lane] + pd[r * 256 + 192 + lane];
                for (int o = 32; o; o >>= 1) s += __shfl_down(s, o);
                if (lane == 0) A.part[r * 256 + bid] = s;
            }
            __syncthreads();
            // per-strip per-row top-10
            u64* kl = (u64*)(smem_raw + 20480);
#pragma unroll
            for (int b = 0; b < BEAM; b++)
                kl[b * 256 + tid] = valid ? (((u64)fkey(lg[b]) << 32) | (unsigned)(~(unsigned)p)) : 0ull;
            __syncthreads();
            for (int r = wv; r < BEAM; r += 4) {
                u64 kk[4];
#pragma unroll
                for (int j = 0; j < 4; j++) kk[j] = kl[r * 256 + j * 64 + lane];
                for (int round = 0; round < BEAM; round++) {
                    u64 m = kk[0];
                    if (kk[1] > m) m = kk[1];
                    if (kk[2] > m) m = kk[2];
                    if (kk[3] > m) m = kk[3];
                    for (int o = 32; o; o >>= 1) {
                        u64 t2 = __shfl_down(m, o);
                        if (t2 > m) m = t2;
                    }
                    u64 win = __shfl(m, 0);
#pragma unroll
                    for (int j = 0; j < 4; j++) if (kk[j] == win) kk[j] = 0ull;
                    if (lane == 0) A.cand[(size_t)r * 2560 + bid * 10 + round] = win;
                }
            }
        }
        gbar2(flags, ++gen);

        // ---- phase RM+M: per-row merge (blocks 0..9) + last-block global merge ----
        if (bid < BEAM) {
            int r = bid;
            double* redd = (double*)(smem_raw + 40960);
            u64* wred = (u64*)(smem_raw + 41024);
            u64* winp = (u64*)(smem_raw + 41056);
            int* lastf = (int*)(smem_raw + 41072);
            // lse
            {
                double s = A.part[r * 256 + tid];
                for (int o = 32; o; o >>= 1) s += __shfl_down(s, o);
                if (lane == 0) redd[wv] = s;
                __syncthreads();
                if (tid == 0) A.lse[r] = log(redd[0] + redd[1] + redd[2] + redd[3]);
            }
            // row top-10 over 2560 strip candidates
            u64 kk[10];
#pragma unroll
            for (int e = 0; e < 10; e++) kk[e] = A.cand[(size_t)r * 2560 + e * 256 + tid];
            for (int round = 0; round < BEAM; round++) {
                u64 m = 0ull;
#pragma unroll
                for (int e = 0; e < 10; e++) if (kk[e] > m) m = kk[e];
                for (int o = 32; o; o >>= 1) {
                    u64 t2 = __shfl_down(m, o);
                    if (t2 > m) m = t2;
                }
                if (lane == 0) wred[wv] = m;
                __syncthreads();
                if (tid == 0) {
                    u64 wn = wred[0];
                    for (int i = 1; i < 4; i++) if (wred[i] > wn) wn = wred[i];
                    *winp = wn;
                    A.rc[r * 10 + round] = wn;
                }
                __syncthreads();
                u64 win = *winp;
#pragma unroll
                for (int e = 0; e < 10; e++) if (kk[e] == win) kk[e] = 0ull;
                __syncthreads();
            }
            // last row-block performs the global merge
            if (tid == 0) {
                int old = __hip_atomic_fetch_add(done, 1, __ATOMIC_ACQ_REL, __HIP_MEMORY_SCOPE_AGENT);
                *lastf = (old == BEAM - 1) ? 1 : 0;
            }
            __syncthreads();
            if (*lastf) {
                MS* M = (MS*)(smem_raw + 41216);
                if (tid < BEAM) { M->scl[tid] = A.sc[tid]; M->lse2[tid] = A.lse[tid]; }
                __syncthreads();
                double cv = -1.0e308; unsigned cf = 0xFFFFFFFFu;
                if (tid < BEAM * BEAM) {
                    u64 k0 = A.rc[tid];
                    if (k0) {
                        int r2 = tid / BEAM;
                        float v = unfkey((unsigned)(k0 >> 32));
                        unsigned p = ~((unsigned)k0);
                        double v2;
                        if (t == 0) v2 = (r2 == 0) ? ((double)v - M->lse2[0]) : NEGD;
                        else        v2 = ((double)v - M->lse2[r2]) + M->scl[r2];
                        cv = v2;
                        cf = (unsigned)r2 * PV + p;
                    }
                }
                for (int round = 0; round < BEAM; round++) {
                    double bv = cv; unsigned bf = cf;
                    for (int o = 32; o; o >>= 1) {
                        double ov = __shfl_down(bv, o);
                        unsigned of = __shfl_down(bf, o);
                        if (ov > bv || (ov == bv && of < bf)) { bv = ov; bf = of; }
                    }
                    if (lane == 0) { M->bwv[wv] = bv; M->bwf[wv] = bf; }
                    __syncthreads();
                    if (tid == 0) {
                        double xv = M->bwv[0]; unsigned xf = M->bwf[0];
                        for (int i = 1; i < 4; i++) {
                            if (M->bwv[i] > xv || (M->bwv[i] == xv && M->bwf[i] < xf)) { xv = M->bwv[i]; xf = M->bwf[i]; }
                        }
                        M->winf = xf;
                        int pk = (int)(xf / PV);
                        int ny = (int)(xf - (unsigned)pk * PV);
                        M->pk[round] = pk; M->ny[round] = ny; M->val[round] = xv;
                    }
                    __syncthreads();
                    if (cf == M->winf) { cv = -1.0e308; cf = 0xFFFFFFFFu; }
                    __syncthreads();
                }
                if (tid < BEAM) {
                    A.sc[tid] = M->val[tid];
                    A.tok[tid] = M->ny[tid];
                    A.prevK[t * BEAM + tid] = M->pk[tid];
                    A.nextY[t * BEAM + tid] = M->ny[tid];
                }
                __syncthreads();
                for (int idx = tid; idx < BEAM * HD; idx += 256) {
                    int i = idx / HD, j = idx - i * HD;
                    A.dh[idx] = A.h2w[M->pk[i] * HD + j];
                    A.dc[idx] = A.c2w[M->pk[i] * HD + j];
                }
                if (tid == 0) __hip_atomic_store(done, 0, __ATOMIC_RELAXED, __HIP_MEMORY_SCOPE_AGENT);
            }
        }
        gbar2(flags, ++gen);
    }

    // ===== traceback =====
    if (bid == 0 && tid < BEAM) {
        int cur = tid;
        for (int tt = MAXLEN - 1; tt >= 0; tt--) {
            A.outTok[tid * MAXLEN + tt] = A.nextY[tt * BEAM + cur];
            cur = A.prevK[tt * BEAM + cur];
        }
    }
}

// ======================================================================
// R4 fallback kernels (used only when ws is too small for the transposed W)
// ======================================================================
__global__ void k_enc(const float* __restrict__ Whh, const float* __restrict__ X,
                      float* __restrict__ gbuf, float* __restrict__ cbuf,
                      float* __restrict__ context, float* __restrict__ dec_h,
                      float* __restrict__ dec_c, double* __restrict__ scores,
                      int* __restrict__ tokens, int t) {
    __shared__ float h_lds[HD];
    const float* gprev = gbuf + ((t + 1) & 1) * G4;
    float*       gcur  = gbuf + (t & 1) * G4;
    const float* cprev = cbuf + ((t + 1) & 1) * HD;
    float*       ccur  = cbuf + (t & 1) * HD;
    int tid = threadIdx.x;
    if (t > 0) {
        for (int j = tid; j < HD; j += 256) {
            float gi = gprev[j], gf = gprev[HD + j], gg = gprev[2 * HD + j], go = gprev[3 * HD + j];
            float c = sigf(gf) * cprev[j] + sigf(gi) * tanhf(gg);
            float h = sigf(go) * tanhf(c);
            h_lds[j] = h;
            if (blockIdx.x == 0) {
                ccur[j] = c;
                context[(t - 1) * HD + j] = h;
                if (t == SLEN) {
                    for (int b = 0; b < BEAM; b++) { dec_h[b * HD + j] = h; dec_c[b * HD + j] = c; }
                }
            }
        }
    } else {
        for (int j = tid; j < HD; j += 256) h_lds[j] = 0.f;
    }
    if (t == SLEN && blockIdx.x == 0 && tid == 0) {
        for (int b = 0; b < BEAM; b++) scores[b] = 0.0;
        tokens[0] = 2; for (int b = 1; b < BEAM; b++) tokens[b] = 1;
    }
    __syncthreads();
    if (t < SLEN) {
        int wv = blockIdx.x * 4 + (tid >> 6), lane = tid & 63;
        for (int r = wv; r < G4; r += 1000) {
            const float* w = Whh + (size_t)r * HD;
            float acc = 0.f;
            for (int ki = 0; ki < 8; ki++) { int k = ki * 64 + lane; if (k < HD) acc += h_lds[k] * w[k]; }
            for (int o = 32; o; o >>= 1) acc += __shfl_down(acc, o);
            if (lane == 0) gcur[r] = X[t * G4 + r] + acc;
        }
    }
}

__global__ __launch_bounds__(1024) void k_gates(
        const float* __restrict__ dec_emb, const float* __restrict__ Wih,
        const float* __restrict__ Whh, const float* __restrict__ bih,
        const float* __restrict__ bhh, const int* __restrict__ tokens,
        const float* __restrict__ h_ws, float* __restrict__ gates) {
    __shared__ float e_lds[BEAM * ED];
    __shared__ float h_lds[BEAM * HD];
    int tid = threadIdx.x;
    for (int idx = tid; idx < BEAM * ED; idx += 1024) {
        int b = idx / ED, k = idx - b * ED;
        e_lds[idx] = dec_emb[(size_t)tokens[b] * ED + k];
        h_lds[idx] = h_ws[idx];
    }
    __syncthreads();
    int wv = tid >> 6, lane = tid & 63;
    int r = blockIdx.x * 16 + wv;
    const float* wi = Wih + (size_t)r * ED;
    const float* wh = Whh + (size_t)r * HD;
    float acc[BEAM];
#pragma unroll
    for (int b = 0; b < BEAM; b++) acc[b] = 0.f;
    for (int ki = 0; ki < 8; ki++) {
        int k = ki * 64 + lane;
        if (k < ED) {
            float w = wi[k];
#pragma unroll
            for (int b = 0; b < BEAM; b++) acc[b] += w * e_lds[b * ED + k];
        }
    }
    for (int ki = 0; ki < 8; ki++) {
        int k = ki * 64 + lane;
        if (k < HD) {
            float w = wh[k];
#pragma unroll
            for (int b = 0; b < BEAM; b++) acc[b] += w * h_lds[b * HD + k];
        }
    }
#pragma unroll
    for (int b = 0; b < BEAM; b++) {
        float v = acc[b];
        for (int o = 32; o; o >>= 1) v += __shfl_down(v, o);
        acc[b] = v;
    }
    if (lane == 0) {
        float bb = bih[r] + bhh[r];
#pragma unroll
        for (int b = 0; b < BEAM; b++) gates[b * G4 + r] = acc[b] + bb;
    }
}

__global__ __launch_bounds__(256) void k_attn_oproj(
        const float* __restrict__ gates, const float* __restrict__ c_ws,
        const float* __restrict__ context, const float* __restrict__ attnW,
        float* __restrict__ h2_ws, float* __restrict__ c2_ws, float* __restrict__ o_ws) {
    __shared__ float h2_lds[BEAM * HD];
    __shared__ float wctx_lds[BEAM * HD];
    __shared__ float s_lds[BEAM * SLEN];
    __shared__ float a_lds[BEAM * SLEN];
    int tid = threadIdx.x;
    int wv = tid >> 6, lane = tid & 63;
    for (int idx = tid; idx < BEAM * HD; idx += 256) {
        int b = idx / HD, j = idx - b * HD;
        float gi = gates[b * G4 + j], gf = gates[b * G4 + HD + j];
        float gg = gates[b * G4 + 2 * HD + j], go = gates[b * G4 + 3 * HD + j];
        float c = sigf(gf) * c_ws[idx] + sigf(gi) * tanhf(gg);
        float h2 = sigf(go) * tanhf(c);
        h2_lds[idx] = h2;
        if (blockIdx.x == 0) { c2_ws[idx] = c; h2_ws[idx] = h2; }
    }
    __syncthreads();
    for (int si = 0; si < 8; ++si) {
        int s = wv + 4 * si;
        float acc[BEAM];
#pragma unroll
        for (int b = 0; b < BEAM; b++) acc[b] = 0.f;
        for (int ki = 0; ki < 8; ki++) {
            int k = ki * 64 + lane;
            if (k < HD) {
                float c = context[s * HD + k];
#pragma unroll
                for (int b = 0; b < BEAM; b++) acc[b] += c * h2_lds[b * HD + k];
            }
        }
#pragma unroll
        for (int b = 0; b < BEAM; b++) {
            float v = acc[b];
            for (int o = 32; o; o >>= 1) v += __shfl_down(v, o);
            if (lane == 0) s_lds[b * SLEN + s] = v;
        }
    }
    __syncthreads();
    if (wv == 0) {
        for (int b = 0; b < BEAM; ++b) {
            float v = (lane < SLEN) ? s_lds[b * SLEN + lane] : -INFINITY;
            float m = v;
            for (int o = 32; o; o >>= 1) m = fmaxf(m, __shfl_xor(m, o));
            float e = (lane < SLEN) ? expf(v - m) : 0.f;
            float sum = e;
            for (int o = 32; o; o >>= 1) sum += __shfl_xor(sum, o);
            if (lane < SLEN) a_lds[b * SLEN + lane] = e / sum;
        }
    }
    __syncthreads();
    {
        float w0[BEAM], w1[BEAM];
#pragma unroll
        for (int b = 0; b < BEAM; b++) { w0[b] = 0.f; w1[b] = 0.f; }
        int j0 = tid, j1 = tid + 256;
        for (int s = 0; s < SLEN; ++s) {
            float c0 = (j0 < HD) ? context[s * HD + j0] : 0.f;
            float c1 = (j1 < HD) ? context[s * HD + j1] : 0.f;
#pragma unroll
            for (int b = 0; b < BEAM; b++) {
                float a = a_lds[b * SLEN + s];
                w0[b] += a * c0; w1[b] += a * c1;
            }
        }
#pragma unroll
        for (int b = 0; b < BEAM; b++) {
            if (j0 < HD) wctx_lds[b * HD + j0] = w0[b];
            if (j1 < HD) wctx_lds[b * HD + j1] = w1[b];
        }
    }
    __syncthreads();
    int j = blockIdx.x * 4 + wv;
    const float* w = attnW + (size_t)j * 1000;
    float acc[BEAM];
#pragma unroll
    for (int b = 0; b < BEAM; b++) acc[b] = 0.f;
    for (int ki = 0; ki < 16; ki++) {
        int k = ki * 64 + lane;
        if (k < 1000) {
            float wk = w[k];
#pragma unroll
            for (int b = 0; b < BEAM; b++) {
                float h = (k < HD) ? h2_lds[b * HD + k] : wctx_lds[b * HD + k - HD];
                acc[b] += wk * h;
            }
        }
    }
#pragma unroll
    for (int b = 0; b < BEAM; b++) {
        float v = acc[b];
        for (int o = 32; o; o >>= 1) v += __shfl_down(v, o);
        acc[b] = v;
    }
    if (lane == 0) {
#pragma unroll
        for (int b = 0; b < BEAM; b++) o_ws[b * HD + j] = tanhf(acc[b]);
    }
}

__global__ void k_logits_f(const float* __restrict__ outW, const float* __restrict__ outB,
                           const float* __restrict__ o_ws, float* __restrict__ logits,
                           double* __restrict__ partials) {
    __shared__ float o_lds[BEAM * HD];
    __shared__ double ered[4][BEAM];
    int tid = threadIdx.x;
    for (int idx = tid; idx < BEAM * HD; idx += 256) o_lds[idx] = o_ws[idx];
    __syncthreads();
    int wv = tid >> 6, lane = tid & 63;
    int w = blockIdx.x * 4 + wv;
    double esum = 0.0;
    for (int pi = 0; pi < 16; pi++) {
        int p = w * 16 + pi;
        if (p >= PV) break;
        const float* wr = outW + (size_t)p * HD;
        float acc[BEAM];
#pragma unroll
        for (int b = 0; b < BEAM; b++) acc[b] = 0.f;
        for (int ki = 0; ki < 8; ki++) {
            int k = ki * 64 + lane;
            if (k < HD) {
                float x = wr[k];
#pragma unroll
                for (int b = 0; b < BEAM; b++) acc[b] += x * o_lds[b * HD + k];
            }
        }
#pragma unroll
        for (int b = 0; b < BEAM; b++)
            for (int o = 32; o; o >>= 1) acc[b] += __shfl_xor(acc[b], o);
        if (lane < BEAM) {
            float lg = 0.f;
#pragma unroll
            for (int b = 0; b < BEAM; b++) if (lane == b) lg = acc[b];
            lg += outB[p];
            logits[(size_t)lane * PV + p] = lg;
            esum += exp((double)lg);
        }
    }
    if (lane < BEAM) ered[wv][lane] = esum;
    __syncthreads();
    if (tid < BEAM) partials[blockIdx.x * BEAM + tid] =
        ered[0][tid] + ered[1][tid] + ered[2][tid] + ered[3][tid];
}

__global__ __launch_bounds__(256) void k_topk_row(const float* __restrict__ logits,
                                                  u64* __restrict__ cands) {
    const int CH = 1563;
    int r = blockIdx.x >> 5, ci = blockIdx.x & 31;
    int base = ci * CH;
    int tid = threadIdx.x;
    int wv = tid >> 6, lane = tid & 63;
    u64 key[7];
#pragma unroll
    for (int e = 0; e < 7; e++) {
        int p = base + e * 256 + tid;
        key[e] = 0ull;
        if (p < base + CH && p < PV) {
            float v = logits[(size_t)r * PV + p];
            key[e] = ((u64)fkey(v) << 32) | (unsigned)(~(unsigned)p);
        }
    }
    __shared__ u64 wred[4];
    __shared__ u64 winlds;
    for (int round = 0; round < BEAM; round++) {
        u64 mx = 0ull;
#pragma unroll
        for (int e = 0; e < 7; e++) if (key[e] > mx) mx = key[e];
        for (int o = 32; o; o >>= 1) {
            u64 other = __shfl_down(mx, o);
            if (other > mx) mx = other;
        }
        if (lane == 0) wred[wv] = mx;
        __syncthreads();
        if (tid == 0) {
            u64 wn = wred[0];
            for (int i = 1; i < 4; i++) if (wred[i] > wn) wn = wred[i];
            winlds = wn;
            cands[blockIdx.x * BEAM + round] = wn;
        }
        __syncthreads();
        u64 win = winlds;
#pragma unroll
        for (int e = 0; e < 7; e++) if (key[e] == win) key[e] = 0ull;
    }
}

__global__ __launch_bounds__(256) void k_merge(
        const double* __restrict__ partials, int npart,
        const u64* __restrict__ cands,
        double* __restrict__ scores, int* __restrict__ tokens,
        const float* __restrict__ h2_ws, const float* __restrict__ c2_ws,
        float* __restrict__ h_ws, float* __restrict__ c_ws,
        int* __restrict__ prevKs, int* __restrict__ nextYs, int t) {
    __shared__ double wredd[4];
    __shared__ double lse_lds[BEAM];
    __shared__ double sc_lds[BEAM];
    __shared__ double bwv[4];
    __shared__ unsigned bwf[4];
    __shared__ unsigned winf_s;
    __shared__ int pk_lds[BEAM];
    __shared__ int ny_lds[BEAM];
    __shared__ double val_lds[BEAM];
    int tid = threadIdx.x;
    int wv = tid >> 6, lane = tid & 63;
    if (tid < BEAM) sc_lds[tid] = scores[tid];
    for (int b = 0; b < BEAM; b++) {
        double s = 0.0;
        for (int j = tid; j < npart; j += 256) s += partials[j * BEAM + b];
        for (int o = 32; o; o >>= 1) s += __shfl_down(s, o);
        if (lane == 0) wredd[wv] = s;
        __syncthreads();
        if (tid == 0) lse_lds[b] = log(wredd[0] + wredd[1] + wredd[2] + wredd[3]);
        __syncthreads();
    }
    double   cv[13];
    unsigned cf[13];
#pragma unroll
    for (int e = 0; e < 13; e++) {
        int c = e * 256 + tid;
        cv[e] = -1.0e308; cf[e] = 0xFFFFFFFFu;
        if (c < 3200) {
            u64 k0 = cands[c];
            if (k0) {
                int r = c / 320;
                float v = unfkey((unsigned)(k0 >> 32));
                unsigned p = ~((unsigned)k0);
                double v2;
                if (t == 0) v2 = (r == 0) ? ((double)v - lse_lds[0]) : (double)NEGF;
                else        v2 = ((double)v - lse_lds[r]) + sc_lds[r];
                cv[e] = v2;
                cf[e] = (unsigned)r * PV + p;
            }
        }
    }
    for (int round = 0; round < BEAM; round++) {
        double bv = -1.0e308; unsigned bf = 0xFFFFFFFFu;
#pragma unroll
        for (int e = 0; e < 13; e++) {
            if (cv[e] > bv || (cv[e] == bv && cf[e] < bf)) { bv = cv[e]; bf = cf[e]; }
        }
        for (int o = 32; o; o >>= 1) {
            double ov = __shfl_down(bv, o);
            unsigned of = __shfl_down(bf, o);
            if (ov > bv || (ov == bv && of < bf)) { bv = ov; bf = of; }
        }
        if (lane == 0) { bwv[wv] = bv; bwf[wv] = bf; }
        __syncthreads();
        if (tid == 0) {
            double xv = bwv[0]; unsigned xf = bwf[0];
            for (int i = 1; i < 4; i++) {
                if (bwv[i] > xv || (bwv[i] == xv && bwf[i] < xf)) { xv = bwv[i]; xf = bwf[i]; }
            }
            winf_s = xf;
            int pk = (int)(xf / PV);
            int ny = (int)(xf - (unsigned)pk * PV);
            pk_lds[round] = pk; ny_lds[round] = ny; val_lds[round] = xv;
        }
        __syncthreads();
        unsigned wff = winf_s;
#pragma unroll
        for (int e = 0; e < 13; e++) {
            if (cf[e] == wff) { cv[e] = -1.0e308; cf[e] = 0xFFFFFFFFu; }
        }
    }
    if (tid < BEAM) {
        scores[tid] = val_lds[tid];
        tokens[tid] = ny_lds[tid];
        prevKs[t * BEAM + tid] = pk_lds[tid];
        nextYs[t * BEAM + tid] = ny_lds[tid];
    }
    __syncthreads();
    for (int idx = tid; idx < BEAM * HD; idx += 256) {
        int i = idx / HD, j = idx - i * HD;
        h_ws[idx] = h2_ws[pk_lds[i] * HD + j];
        c_ws[idx] = c2_ws[pk_lds[i] * HD + j];
    }
}

__global__ void k_traceback(const int* __restrict__ prevKs, const int* __restrict__ nextYs,
                            int* __restrict__ out) {
    int k = threadIdx.x;
    if (k >= BEAM) return;
    int cur = k;
    for (int t = MAXLEN - 1; t >= 0; t--) {
        out[k * MAXLEN + t] = nextYs[t * BEAM + cur];
        cur = prevKs[t * BEAM + cur];
    }
}

extern "C" void kernel_launch(void* const* d_in, const int* in_sizes, int n_in,
                              void* d_out, int out_size, void* d_ws, size_t ws_size,
                              hipStream_t stream) {
    const int*   g_seq  = (const int*)  d_in[0];
    const float* encEmb = (const float*)d_in[1];
    const float* encWih = (const float*)d_in[2];
    const float* encWhh = (const float*)d_in[3];
    const float* encBih = (const float*)d_in[4];
    const float* encBhh = (const float*)d_in[5];
    const float* decEmb = (const float*)d_in[6];
    const float* decWih = (const float*)d_in[7];
    const float* decWhh = (const float*)d_in[8];
    const float* decBih = (const float*)d_in[9];
    const float* decBhh = (const float*)d_in[10];
    const float* attnW  = (const float*)d_in[11];
    const float* outW   = (const float*)d_in[12];
    const float* outB   = (const float*)d_in[13];

    float* ws = (float*)d_ws;
    float*  X     = ws + OFF_X;
    float*  cbuf  = ws + OFF_CBUF;
    float*  gbuf  = ws + OFF_GBUF;
    float*  ctx   = ws + OFF_CTX;
    float*  dh    = ws + OFF_DH;
    float*  dc    = ws + OFF_DC;
    float*  dg    = ws + OFF_DG;
    float*  h2    = ws + OFF_H2;
    float*  c2    = ws + OFF_C2;
    float*  o     = ws + OFF_O;
    double* sc    = (double*)(ws + OFF_SCD);
    int*    tok   = (int*)(ws + OFF_TOK);
    int*    prevK = (int*)(ws + OFF_PREVK);
    int*    nextY = (int*)(ws + OFF_NEXTY);
    int*    bar   = (int*)(ws + OFF_BAR);
    float*  outW4 = ws + OFF_OWT;

    bool bigws = (ws_size >= NEED_T_BYTES);

    k_prep<<<16000, 256, 0, stream>>>(g_seq, encEmb, encWih, encBih, encBhh, X, cbuf, bar);
    if (bigws) k_transpose4<<<dim3(782, 8), 256, 0, stream>>>(outW, outW4);

    if (bigws) {
        // 256 blocks x 256 threads: >=1 block/CU on 256-CU gfx950 regardless of
        // VGPR(<=512)/LDS(44KB<160KB) => all blocks co-resident (verified empirically
        // in rounds 6/7 where the 256-block grid-synced kernel ran to completion).
        MegaA a;
        a.encWhh = encWhh; a.X = X;
        a.gbuf = gbuf; a.cbuf = cbuf; a.ctx = ctx;
        a.decEmb = decEmb; a.decWih = decWih; a.decWhh = decWhh;
        a.decBih = decBih; a.decBhh = decBhh; a.attnW = attnW;
        a.outW4 = outW4; a.outB = outB;
        a.dh = dh; a.dc = dc; a.dg = dg; a.h2w = h2; a.c2w = c2; a.ow = o;
        a.sc = sc; a.part = (double*)(ws + OFF_PARTD); a.lse = (double*)(ws + OFF_LSE);
        a.tok = tok; a.prevK = prevK; a.nextY = nextY;
        a.cand = (u64*)(ws + OFF_CAND); a.rc = (u64*)(ws + OFF_RC);
        a.outTok = (int*)d_out; a.bar = bar;
        k_mega2<<<GRID2, 256, 0, stream>>>(a);
    } else {
        double* part  = (double*)(ws + OFF_PARTF);
        u64*    cand  = (u64*)(ws + OFF_CANDF);
        float*  logits = ws + OFF_LOG;
        for (int t = 0; t <= SLEN; t++)
            k_enc<<<250, 256, 0, stream>>>(encWhh, X, gbuf, cbuf, ctx, dh, dc, sc, tok, t);
        const int npart = 782;
        for (int t = 0; t < MAXLEN; t++) {
            k_gates<<<125, 1024, 0, stream>>>(decEmb, decWih, decWhh, decBih, decBhh, tok, dh, dg);
            k_attn_oproj<<<125, 256, 0, stream>>>(dg, dc, ctx, attnW, h2, c2, o);
            k_logits_f<<<782, 256, 0, stream>>>(outW, outB, o, logits, part);
            k_topk_row<<<320, 256, 0, stream>>>(logits, cand);
            k_merge<<<1, 256, 0, stream>>>(part, npart, cand, sc, tok, h2, c2, dh, dc, prevK, nextY, t);
        }
        k_traceback<<<1, 64, 0, stream>>>(prevK, nextY, (int*)d_out);
    }
}

// Round 9
// 7979.478 us; speedup vs baseline: 1.6215x; 1.6215x over previous
//
#include <hip/hip_runtime.h>
#include <math.h>

#define BEAM   10
#define MAXLEN 32
#define SLEN   32
#define HD     500
#define ED     500
#define G4     2000
#define PV     50000
#define NEGF   (-1e30f)
#define NEGD   (-1.0e30)

#define GRID2  256          // mega grid: 256 blocks x 256 thr = always co-resident on 256-CU gfx950
#define NW     1024         // GRID2*4 waves
#define STRIP  196          // cols per block in logits phase (256*196 >= 50000)

typedef unsigned long long u64;

// ---------------- ws layout (float element offsets) ----------------
#define OFF_X      0
#define OFF_CBUF   64000
#define OFF_GBUF   65000
#define OFF_CTX    69000
#define OFF_DH     85000
#define OFF_DC     90000
#define OFF_DG     95000
#define OFF_H2     115000
#define OFF_C2     120000
#define OFF_O      125000
#define OFF_SCD    135000
#define OFF_TOK    135020
#define OFF_PREVK  135040
#define OFF_NEXTY  135360
// fallback-path regions (R4 layout)
#define OFF_PARTF  136000   // double[7820]
#define OFF_CANDF  152000   // u64[3200]
#define OFF_LOG    160000   // only used by fallback kernels
// mega-path regions (live inside the fallback LOG region; paths are exclusive)
#define OFF_BAR    160000   // int[264]: [0..255] flags, [256] done
#define OFF_LSE    160264   // double[10]
#define OFF_PARTD  160284   // double[10*256]
#define OFF_RC     165404   // u64[100]
#define OFF_CAND   165604   // u64[10*2560]
#define OFF_OWT    660000   // float4-blocked transposed out_W (100 MB)
#define NEED_T_BYTES ((size_t)(OFF_OWT + (size_t)HD * PV) * 4)

__device__ __forceinline__ float sigf(float x) { return 1.f / (1.f + expf(-x)); }

__device__ __forceinline__ unsigned fkey(float f) {
    unsigned u = __float_as_uint(f);
    return (u & 0x80000000u) ? ~u : (u | 0x80000000u);
}
__device__ __forceinline__ float unfkey(unsigned k) {
    unsigned u = (k & 0x80000000u) ? (k & 0x7fffffffu) : ~k;
    return __uint_as_float(u);
}

// Grid barrier, fence-fence pattern.
// R8 lesson: agent-scope ACQUIRE loads emit a cache-invalidate per load and
// RELEASE stores an L2-writeback per store on gfx95x -> a spin loop of acquire
// loads is an invalidate storm (~70us/barrier measured, same as cg grid.sync).
// Here: ONE __threadfence (L2 WB) + relaxed flag store on arrival; spin on
// RELAXED atomic loads (read-through, no invalidate); ONE __threadfence (inv)
// after all flags observed, sequenced by __syncthreads before any data reads.
// All GRID2 blocks are co-resident (1 block/CU; empirically verified R6-R8),
// so spinning is deadlock-free.
__device__ __forceinline__ void gbar2(int* flags, int gen) {
    __syncthreads();   // all waves' prior mem ops drained (vmcnt0 before s_barrier)
    if (threadIdx.x == 0) {
        __threadfence();   // release: flush this block's writes to coherence point
        __hip_atomic_store(&flags[blockIdx.x], gen, __ATOMIC_RELAXED, __HIP_MEMORY_SCOPE_AGENT);
    }
    if (threadIdx.x < 64) {
        int l = threadIdx.x;
        for (;;) {
            int v0 = __hip_atomic_load(&flags[l],       __ATOMIC_RELAXED, __HIP_MEMORY_SCOPE_AGENT);
            int v1 = __hip_atomic_load(&flags[l + 64],  __ATOMIC_RELAXED, __HIP_MEMORY_SCOPE_AGENT);
            int v2 = __hip_atomic_load(&flags[l + 128], __ATOMIC_RELAXED, __HIP_MEMORY_SCOPE_AGENT);
            int v3 = __hip_atomic_load(&flags[l + 192], __ATOMIC_RELAXED, __HIP_MEMORY_SCOPE_AGENT);
            bool ok = (v0 >= gen) && (v1 >= gen) && (v2 >= gen) && (v3 >= gen);
            if (__all(ok)) break;
            __builtin_amdgcn_s_sleep(2);
        }
    }
    __syncthreads();   // whole block waits for wave 0's spin
    if (threadIdx.x == 0) __threadfence();   // acquire: invalidate stale L1/L2 once
    __syncthreads();   // fence ordered before any thread's data reads
}

// ---------------- prep (also resets barrier state every call/replay) ----------------
__global__ void k_prep(const int* __restrict__ g_seq, const float* __restrict__ enc_emb,
                       const float* __restrict__ Wih, const float* __restrict__ bih,
                       const float* __restrict__ bhh, float* __restrict__ X,
                       float* __restrict__ cbuf0, int* __restrict__ bar) {
    if (blockIdx.x == 0) {
        for (int j = threadIdx.x; j < HD; j += 256) cbuf0[j] = 0.f;
        for (int j = threadIdx.x; j < 264; j += 256) bar[j] = 0;
    }
    int wv = (blockIdx.x * blockDim.x + threadIdx.x) >> 6;
    int lane = threadIdx.x & 63;
    if (wv >= SLEN * G4) return;
    int t = wv / G4, r = wv - t * G4;
    const float* emb = enc_emb + (size_t)g_seq[t] * ED;
    const float* w = Wih + (size_t)r * ED;
    float acc = 0.f;
    for (int ki = 0; ki < 8; ki++) { int k = ki * 64 + lane; if (k < ED) acc += emb[k] * w[k]; }
    for (int o = 32; o; o >>= 1) acc += __shfl_down(acc, o);
    if (lane == 0) X[t * G4 + r] = acc + bih[r] + bhh[r];
}

// ---------------- out_W blocked transpose ----------------
__global__ void k_transpose4(const float* __restrict__ outW, float* __restrict__ outW4) {
    __shared__ float t_lds[64][65];
    int tid = threadIdx.x;
    int pbase = blockIdx.x * 64, kbase = blockIdx.y * 64;
    for (int e = 0; e < 16; e++) {
        int idx = e * 256 + tid; int pl = idx >> 6, kl = idx & 63;
        int pp = pbase + pl, kk = kbase + kl;
        t_lds[pl][kl] = (pp < PV && kk < HD) ? outW[(size_t)pp * HD + kk] : 0.f;
    }
    __syncthreads();
    for (int e = 0; e < 4; e++) {
        int idx = e * 256 + tid;
        int pl = idx & 63, kb = idx >> 6;
        int pp = pbase + pl;
        int kglob = kbase + kb * 4;
        if (pp < PV && kglob < HD) {
            float4 v;
            v.x = t_lds[pl][kb * 4 + 0];
            v.y = t_lds[pl][kb * 4 + 1];
            v.z = t_lds[pl][kb * 4 + 2];
            v.w = t_lds[pl][kb * 4 + 3];
            *(float4*)(outW4 + ((size_t)(kbase / 4 + kb) * PV + pp) * 4) = v;
        }
    }
}

// ================= mega args =================
struct MegaA {
    const float* encWhh; const float* X;
    float* gbuf; float* cbuf; float* ctx;
    const float* decEmb; const float* decWih; const float* decWhh;
    const float* decBih; const float* decBhh; const float* attnW;
    const float* outW4; const float* outB;
    float* dh; float* dc; float* dg; float* h2w; float* c2w; float* ow;
    double* sc; double* part; double* lse;
    int* tok; int* prevK; int* nextY; u64* cand; u64* rc; int* outTok;
    int* bar;   // [0..255] flags, [256] done
};

struct MS {
    double scl[BEAM]; double lse2[BEAM];
    double bwv[4]; unsigned bwf[4]; unsigned winf;
    int pk[BEAM]; int ny[BEAM]; double val[BEAM];
};

// ================= persistent mega (normal launch, fence-fence barrier) =================
__global__ __launch_bounds__(256) void k_mega2(MegaA A) {
    __shared__ __align__(16) char smem_raw[44032];
    float* smf = (float*)smem_raw;
    int* flags = A.bar;
    int* done  = A.bar + 256;
    int gen = 0;
    const int tid = threadIdx.x, bid = blockIdx.x;
    const int wv = tid >> 6, lane = tid & 63;
    const int gw = bid * 4 + wv;

    // ===== encoder: 33 steps =====
    for (int t = 0; t <= SLEN; ++t) {
        const float* gprev = A.gbuf + ((t + 1) & 1) * G4;
        float*       gcur  = A.gbuf + (t & 1) * G4;
        const float* cprev = A.cbuf + ((t + 1) & 1) * HD;
        float*       ccur  = A.cbuf + (t & 1) * HD;
        if (t < SLEN || bid == 0) {
            float* h_lds = smf;
            if (t > 0) {
                for (int j = tid; j < HD; j += 256) {
                    float gi = gprev[j], gf = gprev[HD + j], gg = gprev[2 * HD + j], go = gprev[3 * HD + j];
                    float c = sigf(gf) * cprev[j] + sigf(gi) * tanhf(gg);
                    float h = sigf(go) * tanhf(c);
                    h_lds[j] = h;
                    if (bid == 0) {
                        ccur[j] = c;
                        A.ctx[(t - 1) * HD + j] = h;
                        if (t == SLEN) {
                            for (int b = 0; b < BEAM; b++) { A.dh[b * HD + j] = h; A.dc[b * HD + j] = c; }
                        }
                    }
                }
            } else {
                for (int j = tid; j < HD; j += 256) h_lds[j] = 0.f;
            }
            if (t == SLEN && bid == 0 && tid == 0) {
                for (int b = 0; b < BEAM; b++) A.sc[b] = 0.0;
                A.tok[0] = 2; for (int b = 1; b < BEAM; b++) A.tok[b] = 1;
            }
            __syncthreads();
            if (t < SLEN) {
                for (int r = gw; r < G4; r += NW) {
                    const float* w = A.encWhh + (size_t)r * HD;
                    float acc = 0.f;
                    for (int ki = 0; ki < 8; ki++) { int k = ki * 64 + lane; if (k < HD) acc += h_lds[k] * w[k]; }
                    for (int o = 32; o; o >>= 1) acc += __shfl_down(acc, o);
                    if (lane == 0) gcur[r] = A.X[t * G4 + r] + acc;
                }
            }
        }
        gbar2(flags, ++gen);
    }

    // ===== decode: 32 steps x 4 barriers =====
    for (int t = 0; t < MAXLEN; ++t) {
        // ---- phase G: gates (all 256 blocks, rows strided) ----
        {
            float* e_lds = smf;               // 5000
            float* h_lds = smf + 5000;        // 5000
            for (int idx = tid; idx < BEAM * ED; idx += 256) {
                int b = idx / ED, k = idx - b * ED;
                e_lds[idx] = A.decEmb[(size_t)A.tok[b] * ED + k];
                h_lds[idx] = A.dh[idx];
            }
            __syncthreads();
            for (int r = gw; r < G4; r += NW) {
                const float* wi = A.decWih + (size_t)r * ED;
                const float* wh = A.decWhh + (size_t)r * HD;
                float acc[BEAM];
#pragma unroll
                for (int b = 0; b < BEAM; b++) acc[b] = 0.f;
                for (int ki = 0; ki < 8; ki++) {
                    int k = ki * 64 + lane;
                    if (k < ED) {
                        float w = wi[k];
#pragma unroll
                        for (int b = 0; b < BEAM; b++) acc[b] += w * e_lds[b * ED + k];
                    }
                }
                for (int ki = 0; ki < 8; ki++) {
                    int k = ki * 64 + lane;
                    if (k < HD) {
                        float w = wh[k];
#pragma unroll
                        for (int b = 0; b < BEAM; b++) acc[b] += w * h_lds[b * HD + k];
                    }
                }
#pragma unroll
                for (int b = 0; b < BEAM; b++) {
                    float v = acc[b];
                    for (int o = 32; o; o >>= 1) v += __shfl_down(v, o);
                    acc[b] = v;
                }
                if (lane == 0) {
                    float bb = A.decBih[r] + A.decBhh[r];
#pragma unroll
                    for (int b = 0; b < BEAM; b++) A.dg[b * G4 + r] = acc[b] + bb;
                }
            }
        }
        gbar2(flags, ++gen);

        // ---- phase A: LSTM pointwise + attention + oproj (blocks 0..124) ----
        if (bid < 125) {
            float* h2_lds   = smf;
            float* wctx_lds = smf + 5000;
            float* s_lds    = smf + 10000;
            float* a_lds    = smf + 10320;
            for (int idx = tid; idx < BEAM * HD; idx += 256) {
                int b = idx / HD, j = idx - b * HD;
                float gi = A.dg[b * G4 + j], gf = A.dg[b * G4 + HD + j];
                float gg = A.dg[b * G4 + 2 * HD + j], go = A.dg[b * G4 + 3 * HD + j];
                float c = sigf(gf) * A.dc[idx] + sigf(gi) * tanhf(gg);
                float h2 = sigf(go) * tanhf(c);
                h2_lds[idx] = h2;
                if (bid == 0) { A.c2w[idx] = c; A.h2w[idx] = h2; }
            }
            __syncthreads();
            for (int si = 0; si < 8; ++si) {
                int s = wv + 4 * si;
                float acc[BEAM];
#pragma unroll
                for (int b = 0; b < BEAM; b++) acc[b] = 0.f;
                for (int ki = 0; ki < 8; ki++) {
                    int k = ki * 64 + lane;
                    if (k < HD) {
                        float c = A.ctx[s * HD + k];
#pragma unroll
                        for (int b = 0; b < BEAM; b++) acc[b] += c * h2_lds[b * HD + k];
                    }
                }
#pragma unroll
                for (int b = 0; b < BEAM; b++) {
                    float v = acc[b];
                    for (int o = 32; o; o >>= 1) v += __shfl_down(v, o);
                    if (lane == 0) s_lds[b * SLEN + s] = v;
                }
            }
            __syncthreads();
            if (wv == 0) {
                for (int b = 0; b < BEAM; ++b) {
                    float v = (lane < SLEN) ? s_lds[b * SLEN + lane] : -INFINITY;
                    float m = v;
                    for (int o = 32; o; o >>= 1) m = fmaxf(m, __shfl_xor(m, o));
                    float e = (lane < SLEN) ? expf(v - m) : 0.f;
                    float sum = e;
                    for (int o = 32; o; o >>= 1) sum += __shfl_xor(sum, o);
                    if (lane < SLEN) a_lds[b * SLEN + lane] = e / sum;
                }
            }
            __syncthreads();
            {
                float w0[BEAM], w1[BEAM];
#pragma unroll
                for (int b = 0; b < BEAM; b++) { w0[b] = 0.f; w1[b] = 0.f; }
                int j0 = tid, j1 = tid + 256;
                for (int s = 0; s < SLEN; ++s) {
                    float c0 = (j0 < HD) ? A.ctx[s * HD + j0] : 0.f;
                    float c1 = (j1 < HD) ? A.ctx[s * HD + j1] : 0.f;
#pragma unroll
                    for (int b = 0; b < BEAM; b++) {
                        float a = a_lds[b * SLEN + s];
                        w0[b] += a * c0; w1[b] += a * c1;
                    }
                }
#pragma unroll
                for (int b = 0; b < BEAM; b++) {
                    if (j0 < HD) wctx_lds[b * HD + j0] = w0[b];
                    if (j1 < HD) wctx_lds[b * HD + j1] = w1[b];
                }
            }
            __syncthreads();
            int j = gw;
            const float* w = A.attnW + (size_t)j * 1000;
            float acc[BEAM];
#pragma unroll
            for (int b = 0; b < BEAM; b++) acc[b] = 0.f;
            for (int ki = 0; ki < 16; ki++) {
                int k = ki * 64 + lane;
                if (k < 1000) {
                    float wk = w[k];
#pragma unroll
                    for (int b = 0; b < BEAM; b++) {
                        float h = (k < HD) ? h2_lds[b * HD + k] : wctx_lds[b * HD + k - HD];
                        acc[b] += wk * h;
                    }
                }
            }
#pragma unroll
            for (int b = 0; b < BEAM; b++) {
                float v = acc[b];
                for (int o = 32; o; o >>= 1) v += __shfl_down(v, o);
                acc[b] = v;
            }
            if (lane == 0) {
#pragma unroll
                for (int b = 0; b < BEAM; b++) A.ow[b * HD + j] = tanhf(acc[b]);
            }
        }
        gbar2(flags, ++gen);

        // ---- phase L+T: logits (1 col/thread) + per-strip top-10 + fp64 partial sumexp ----
        {
            float4* o4 = (float4*)smem_raw;   // 1250 float4 = 20000 B
            for (int idx = tid; idx < BEAM * 125; idx += 256) {
                int b = idx / 125, kb = idx - b * 125;
                o4[idx] = *(const float4*)(A.ow + b * HD + kb * 4);
            }
            __syncthreads();
            int p = bid * STRIP + tid;
            bool valid = (tid < STRIP) && (p < PV);
            int pc = (p < PV) ? p : (PV - 1);
            float lg[BEAM];
            {
                float acc[BEAM];
#pragma unroll
                for (int b = 0; b < BEAM; b++) acc[b] = 0.f;
                const float4* wp = (const float4*)A.outW4;
                for (int kb = 0; kb < 125; ++kb) {
                    float4 w = wp[(size_t)kb * PV + pc];
#pragma unroll
                    for (int b = 0; b < BEAM; b++) {
                        float4 o = o4[b * 125 + kb];
                        acc[b] += w.x * o.x + w.y * o.y + w.z * o.z + w.w * o.w;
                    }
                }
                float ob = A.outB[pc];
#pragma unroll
                for (int b = 0; b < BEAM; b++) lg[b] = acc[b] + ob;
            }
            // fp64 partial sumexp per row
            double* pd = (double*)(smem_raw + 20480);
#pragma unroll
            for (int b = 0; b < BEAM; b++) pd[b * 256 + tid] = valid ? exp((double)lg[b]) : 0.0;
            __syncthreads();
            for (int r = wv; r < BEAM; r += 4) {
                double s = pd[r * 256 + lane] + pd[r * 256 + 64 + lane]
                         + pd[r * 256 + 128 + lane] + pd[r * 256 + 192 + lane];
                for (int o = 32; o; o >>= 1) s += __shfl_down(s, o);
                if (lane == 0) A.part[r * 256 + bid] = s;
            }
            __syncthreads();
            // per-strip per-row top-10
            u64* kl = (u64*)(smem_raw + 20480);
#pragma unroll
            for (int b = 0; b < BEAM; b++)
                kl[b * 256 + tid] = valid ? (((u64)fkey(lg[b]) << 32) | (unsigned)(~(unsigned)p)) : 0ull;
            __syncthreads();
            for (int r = wv; r < BEAM; r += 4) {
                u64 kk[4];
#pragma unroll
                for (int j = 0; j < 4; j++) kk[j] = kl[r * 256 + j * 64 + lane];
                for (int round = 0; round < BEAM; round++) {
                    u64 m = kk[0];
                    if (kk[1] > m) m = kk[1];
                    if (kk[2] > m) m = kk[2];
                    if (kk[3] > m) m = kk[3];
                    for (int o = 32; o; o >>= 1) {
                        u64 t2 = __shfl_down(m, o);
                        if (t2 > m) m = t2;
                    }
                    u64 win = __shfl(m, 0);
#pragma unroll
                    for (int j = 0; j < 4; j++) if (kk[j] == win) kk[j] = 0ull;
                    if (lane == 0) A.cand[(size_t)r * 2560 + bid * 10 + round] = win;
                }
            }
        }
        gbar2(flags, ++gen);

        // ---- phase RM+M: per-row merge (blocks 0..9) + last-block global merge ----
        if (bid < BEAM) {
            int r = bid;
            double* redd = (double*)(smem_raw + 40960);
            u64* wred = (u64*)(smem_raw + 41024);
            u64* winp = (u64*)(smem_raw + 41056);
            int* lastf = (int*)(smem_raw + 41072);
            // lse
            {
                double s = A.part[r * 256 + tid];
                for (int o = 32; o; o >>= 1) s += __shfl_down(s, o);
                if (lane == 0) redd[wv] = s;
                __syncthreads();
                if (tid == 0) A.lse[r] = log(redd[0] + redd[1] + redd[2] + redd[3]);
            }
            // row top-10 over 2560 strip candidates
            u64 kk[10];
#pragma unroll
            for (int e = 0; e < 10; e++) kk[e] = A.cand[(size_t)r * 2560 + e * 256 + tid];
            for (int round = 0; round < BEAM; round++) {
                u64 m = 0ull;
#pragma unroll
                for (int e = 0; e < 10; e++) if (kk[e] > m) m = kk[e];
                for (int o = 32; o; o >>= 1) {
                    u64 t2 = __shfl_down(m, o);
                    if (t2 > m) m = t2;
                }
                if (lane == 0) wred[wv] = m;
                __syncthreads();
                if (tid == 0) {
                    u64 wn = wred[0];
                    for (int i = 1; i < 4; i++) if (wred[i] > wn) wn = wred[i];
                    *winp = wn;
                    A.rc[r * 10 + round] = wn;
                }
                __syncthreads();
                u64 win = *winp;
#pragma unroll
                for (int e = 0; e < 10; e++) if (kk[e] == win) kk[e] = 0ull;
                __syncthreads();
            }
            // last row-block performs the global merge
            if (tid == 0) {
                int old = __hip_atomic_fetch_add(done, 1, __ATOMIC_ACQ_REL, __HIP_MEMORY_SCOPE_AGENT);
                *lastf = (old == BEAM - 1) ? 1 : 0;
            }
            __syncthreads();
            if (*lastf) {
                MS* M = (MS*)(smem_raw + 41216);
                if (tid < BEAM) { M->scl[tid] = A.sc[tid]; M->lse2[tid] = A.lse[tid]; }
                __syncthreads();
                double cv = -1.0e308; unsigned cf = 0xFFFFFFFFu;
                if (tid < BEAM * BEAM) {
                    u64 k0 = A.rc[tid];
                    if (k0) {
                        int r2 = tid / BEAM;
                        float v = unfkey((unsigned)(k0 >> 32));
                        unsigned p = ~((unsigned)k0);
                        double v2;
                        if (t == 0) v2 = (r2 == 0) ? ((double)v - M->lse2[0]) : NEGD;
                        else        v2 = ((double)v - M->lse2[r2]) + M->scl[r2];
                        cv = v2;
                        cf = (unsigned)r2 * PV + p;
                    }
                }
                for (int round = 0; round < BEAM; round++) {
                    double bv = cv; unsigned bf = cf;
                    for (int o = 32; o; o >>= 1) {
                        double ov = __shfl_down(bv, o);
                        unsigned of = __shfl_down(bf, o);
                        if (ov > bv || (ov == bv && of < bf)) { bv = ov; bf = of; }
                    }
                    if (lane == 0) { M->bwv[wv] = bv; M->bwf[wv] = bf; }
                    __syncthreads();
                    if (tid == 0) {
                        double xv = M->bwv[0]; unsigned xf = M->bwf[0];
                        for (int i = 1; i < 4; i++) {
                            if (M->bwv[i] > xv || (M->bwv[i] == xv && M->bwf[i] < xf)) { xv = M->bwv[i]; xf = M->bwf[i]; }
                        }
                        M->winf = xf;
                        int pk = (int)(xf / PV);
                        int ny = (int)(xf - (unsigned)pk * PV);
                        M->pk[round] = pk; M->ny[round] = ny; M->val[round] = xv;
                    }
                    __syncthreads();
                    if (cf == M->winf) { cv = -1.0e308; cf = 0xFFFFFFFFu; }
                    __syncthreads();
                }
                if (tid < BEAM) {
                    A.sc[tid] = M->val[tid];
                    A.tok[tid] = M->ny[tid];
                    A.prevK[t * BEAM + tid] = M->pk[tid];
                    A.nextY[t * BEAM + tid] = M->ny[tid];
                }
                __syncthreads();
                for (int idx = tid; idx < BEAM * HD; idx += 256) {
                    int i = idx / HD, j = idx - i * HD;
                    A.dh[idx] = A.h2w[M->pk[i] * HD + j];
                    A.dc[idx] = A.c2w[M->pk[i] * HD + j];
                }
                if (tid == 0) __hip_atomic_store(done, 0, __ATOMIC_RELAXED, __HIP_MEMORY_SCOPE_AGENT);
            }
        }
        gbar2(flags, ++gen);
    }

    // ===== traceback =====
    if (bid == 0 && tid < BEAM) {
        int cur = tid;
        for (int tt = MAXLEN - 1; tt >= 0; tt--) {
            A.outTok[tid * MAXLEN + tt] = A.nextY[tt * BEAM + cur];
            cur = A.prevK[tt * BEAM + cur];
        }
    }
}

// ======================================================================
// R4 fallback kernels (used only when ws is too small for the transposed W)
// ======================================================================
__global__ void k_enc(const float* __restrict__ Whh, const float* __restrict__ X,
                      float* __restrict__ gbuf, float* __restrict__ cbuf,
                      float* __restrict__ context, float* __restrict__ dec_h,
                      float* __restrict__ dec_c, double* __restrict__ scores,
                      int* __restrict__ tokens, int t) {
    __shared__ float h_lds[HD];
    const float* gprev = gbuf + ((t + 1) & 1) * G4;
    float*       gcur  = gbuf + (t & 1) * G4;
    const float* cprev = cbuf + ((t + 1) & 1) * HD;
    float*       ccur  = cbuf + (t & 1) * HD;
    int tid = threadIdx.x;
    if (t > 0) {
        for (int j = tid; j < HD; j += 256) {
            float gi = gprev[j], gf = gprev[HD + j], gg = gprev[2 * HD + j], go = gprev[3 * HD + j];
            float c = sigf(gf) * cprev[j] + sigf(gi) * tanhf(gg);
            float h = sigf(go) * tanhf(c);
            h_lds[j] = h;
            if (blockIdx.x == 0) {
                ccur[j] = c;
                context[(t - 1) * HD + j] = h;
                if (t == SLEN) {
                    for (int b = 0; b < BEAM; b++) { dec_h[b * HD + j] = h; dec_c[b * HD + j] = c; }
                }
            }
        }
    } else {
        for (int j = tid; j < HD; j += 256) h_lds[j] = 0.f;
    }
    if (t == SLEN && blockIdx.x == 0 && tid == 0) {
        for (int b = 0; b < BEAM; b++) scores[b] = 0.0;
        tokens[0] = 2; for (int b = 1; b < BEAM; b++) tokens[b] = 1;
    }
    __syncthreads();
    if (t < SLEN) {
        int wv = blockIdx.x * 4 + (tid >> 6), lane = tid & 63;
        for (int r = wv; r < G4; r += 1000) {
            const float* w = Whh + (size_t)r * HD;
            float acc = 0.f;
            for (int ki = 0; ki < 8; ki++) { int k = ki * 64 + lane; if (k < HD) acc += h_lds[k] * w[k]; }
            for (int o = 32; o; o >>= 1) acc += __shfl_down(acc, o);
            if (lane == 0) gcur[r] = X[t * G4 + r] + acc;
        }
    }
}

__global__ __launch_bounds__(1024) void k_gates(
        const float* __restrict__ dec_emb, const float* __restrict__ Wih,
        const float* __restrict__ Whh, const float* __restrict__ bih,
        const float* __restrict__ bhh, const int* __restrict__ tokens,
        const float* __restrict__ h_ws, float* __restrict__ gates) {
    __shared__ float e_lds[BEAM * ED];
    __shared__ float h_lds[BEAM * HD];
    int tid = threadIdx.x;
    for (int idx = tid; idx < BEAM * ED; idx += 1024) {
        int b = idx / ED, k = idx - b * ED;
        e_lds[idx] = dec_emb[(size_t)tokens[b] * ED + k];
        h_lds[idx] = h_ws[idx];
    }
    __syncthreads();
    int wv = tid >> 6, lane = tid & 63;
    int r = blockIdx.x * 16 + wv;
    const float* wi = Wih + (size_t)r * ED;
    const float* wh = Whh + (size_t)r * HD;
    float acc[BEAM];
#pragma unroll
    for (int b = 0; b < BEAM; b++) acc[b] = 0.f;
    for (int ki = 0; ki < 8; ki++) {
        int k = ki * 64 + lane;
        if (k < ED) {
            float w = wi[k];
#pragma unroll
            for (int b = 0; b < BEAM; b++) acc[b] += w * e_lds[b * ED + k];
        }
    }
    for (int ki = 0; ki < 8; ki++) {
        int k = ki * 64 + lane;
        if (k < HD) {
            float w = wh[k];
#pragma unroll
            for (int b = 0; b < BEAM; b++) acc[b] += w * h_lds[b * HD + k];
        }
    }
#pragma unroll
    for (int b = 0; b < BEAM; b++) {
        float v = acc[b];
        for (int o = 32; o; o >>= 1) v += __shfl_down(v, o);
        acc[b] = v;
    }
    if (lane == 0) {
        float bb = bih[r] + bhh[r];
#pragma unroll
        for (int b = 0; b < BEAM; b++) gates[b * G4 + r] = acc[b] + bb;
    }
}

__global__ __launch_bounds__(256) void k_attn_oproj(
        const float* __restrict__ gates, const float* __restrict__ c_ws,
        const float* __restrict__ context, const float* __restrict__ attnW,
        float* __restrict__ h2_ws, float* __restrict__ c2_ws, float* __restrict__ o_ws) {
    __shared__ float h2_lds[BEAM * HD];
    __shared__ float wctx_lds[BEAM * HD];
    __shared__ float s_lds[BEAM * SLEN];
    __shared__ float a_lds[BEAM * SLEN];
    int tid = threadIdx.x;
    int wv = tid >> 6, lane = tid & 63;
    for (int idx = tid; idx < BEAM * HD; idx += 256) {
        int b = idx / HD, j = idx - b * HD;
        float gi = gates[b * G4 + j], gf = gates[b * G4 + HD + j];
        float gg = gates[b * G4 + 2 * HD + j], go = gates[b * G4 + 3 * HD + j];
        float c = sigf(gf) * c_ws[idx] + sigf(gi) * tanhf(gg);
        float h2 = sigf(go) * tanhf(c);
        h2_lds[idx] = h2;
        if (blockIdx.x == 0) { c2_ws[idx] = c; h2_ws[idx] = h2; }
    }
    __syncthreads();
    for (int si = 0; si < 8; ++si) {
        int s = wv + 4 * si;
        float acc[BEAM];
#pragma unroll
        for (int b = 0; b < BEAM; b++) acc[b] = 0.f;
        for (int ki = 0; ki < 8; ki++) {
            int k = ki * 64 + lane;
            if (k < HD) {
                float c = context[s * HD + k];
#pragma unroll
                for (int b = 0; b < BEAM; b++) acc[b] += c * h2_lds[b * HD + k];
            }
        }
#pragma unroll
        for (int b = 0; b < BEAM; b++) {
            float v = acc[b];
            for (int o = 32; o; o >>= 1) v += __shfl_down(v, o);
            if (lane == 0) s_lds[b * SLEN + s] = v;
        }
    }
    __syncthreads();
    if (wv == 0) {
        for (int b = 0; b < BEAM; ++b) {
            float v = (lane < SLEN) ? s_lds[b * SLEN + lane] : -INFINITY;
            float m = v;
            for (int o = 32; o; o >>= 1) m = fmaxf(m, __shfl_xor(m, o));
            float e = (lane < SLEN) ? expf(v - m) : 0.f;
            float sum = e;
            for (int o = 32; o; o >>= 1) sum += __shfl_xor(sum, o);
            if (lane < SLEN) a_lds[b * SLEN + lane] = e / sum;
        }
    }
    __syncthreads();
    {
        float w0[BEAM], w1[BEAM];
#pragma unroll
        for (int b = 0; b < BEAM; b++) { w0[b] = 0.f; w1[b] = 0.f; }
        int j0 = tid, j1 = tid + 256;
        for (int s = 0; s < SLEN; ++s) {
            float c0 = (j0 < HD) ? context[s * HD + j0] : 0.f;
            float c1 = (j1 < HD) ? context[s * HD + j1] : 0.f;
#pragma unroll
            for (int b = 0; b < BEAM; b++) {
                float a = a_lds[b * SLEN + s];
                w0[b] += a * c0; w1[b] += a * c1;
            }
        }
#pragma unroll
        for (int b = 0; b < BEAM; b++) {
            if (j0 < HD) wctx_lds[b * HD + j0] = w0[b];
            if (j1 < HD) wctx_lds[b * HD + j1] = w1[b];
        }
    }
    __syncthreads();
    int j = blockIdx.x * 4 + wv;
    const float* w = attnW + (size_t)j * 1000;
    float acc[BEAM];
#pragma unroll
    for (int b = 0; b < BEAM; b++) acc[b] = 0.f;
    for (int ki = 0; ki < 16; ki++) {
        int k = ki * 64 + lane;
        if (k < 1000) {
            float wk = w[k];
#pragma unroll
            for (int b = 0; b < BEAM; b++) {
                float h = (k < HD) ? h2_lds[b * HD + k] : wctx_lds[b * HD + k - HD];
                acc[b] += wk * h;
            }
        }
    }
#pragma unroll
    for (int b = 0; b < BEAM; b++) {
        float v = acc[b];
        for (int o = 32; o; o >>= 1) v += __shfl_down(v, o);
        acc[b] = v;
    }
    if (lane == 0) {
#pragma unroll
        for (int b = 0; b < BEAM; b++) o_ws[b * HD + j] = tanhf(acc[b]);
    }
}

__global__ void k_logits_f(const float* __restrict__ outW, const float* __restrict__ outB,
                           const float* __restrict__ o_ws, float* __restrict__ logits,
                           double* __restrict__ partials) {
    __shared__ float o_lds[BEAM * HD];
    __shared__ double ered[4][BEAM];
    int tid = threadIdx.x;
    for (int idx = tid; idx < BEAM * HD; idx += 256) o_lds[idx] = o_ws[idx];
    __syncthreads();
    int wv = tid >> 6, lane = tid & 63;
    int w = blockIdx.x * 4 + wv;
    double esum = 0.0;
    for (int pi = 0; pi < 16; pi++) {
        int p = w * 16 + pi;
        if (p >= PV) break;
        const float* wr = outW + (size_t)p * HD;
        float acc[BEAM];
#pragma unroll
        for (int b = 0; b < BEAM; b++) acc[b] = 0.f;
        for (int ki = 0; ki < 8; ki++) {
            int k = ki * 64 + lane;
            if (k < HD) {
                float x = wr[k];
#pragma unroll
                for (int b = 0; b < BEAM; b++) acc[b] += x * o_lds[b * HD + k];
            }
        }
#pragma unroll
        for (int b = 0; b < BEAM; b++)
            for (int o = 32; o; o >>= 1) acc[b] += __shfl_xor(acc[b], o);
        if (lane < BEAM) {
            float lg = 0.f;
#pragma unroll
            for (int b = 0; b < BEAM; b++) if (lane == b) lg = acc[b];
            lg += outB[p];
            logits[(size_t)lane * PV + p] = lg;
            esum += exp((double)lg);
        }
    }
    if (lane < BEAM) ered[wv][lane] = esum;
    __syncthreads();
    if (tid < BEAM) partials[blockIdx.x * BEAM + tid] =
        ered[0][tid] + ered[1][tid] + ered[2][tid] + ered[3][tid];
}

__global__ __launch_bounds__(256) void k_topk_row(const float* __restrict__ logits,
                                                  u64* __restrict__ cands) {
    const int CH = 1563;
    int r = blockIdx.x >> 5, ci = blockIdx.x & 31;
    int base = ci * CH;
    int tid = threadIdx.x;
    int wv = tid >> 6, lane = tid & 63;
    u64 key[7];
#pragma unroll
    for (int e = 0; e < 7; e++) {
        int p = base + e * 256 + tid;
        key[e] = 0ull;
        if (p < base + CH && p < PV) {
            float v = logits[(size_t)r * PV + p];
            key[e] = ((u64)fkey(v) << 32) | (unsigned)(~(unsigned)p);
        }
    }
    __shared__ u64 wred[4];
    __shared__ u64 winlds;
    for (int round = 0; round < BEAM; round++) {
        u64 mx = 0ull;
#pragma unroll
        for (int e = 0; e < 7; e++) if (key[e] > mx) mx = key[e];
        for (int o = 32; o; o >>= 1) {
            u64 other = __shfl_down(mx, o);
            if (other > mx) mx = other;
        }
        if (lane == 0) wred[wv] = mx;
        __syncthreads();
        if (tid == 0) {
            u64 wn = wred[0];
            for (int i = 1; i < 4; i++) if (wred[i] > wn) wn = wred[i];
            winlds = wn;
            cands[blockIdx.x * BEAM + round] = wn;
        }
        __syncthreads();
        u64 win = winlds;
#pragma unroll
        for (int e = 0; e < 7; e++) if (key[e] == win) key[e] = 0ull;
    }
}

__global__ __launch_bounds__(256) void k_merge(
        const double* __restrict__ partials, int npart,
        const u64* __restrict__ cands,
        double* __restrict__ scores, int* __restrict__ tokens,
        const float* __restrict__ h2_ws, const float* __restrict__ c2_ws,
        float* __restrict__ h_ws, float* __restrict__ c_ws,
        int* __restrict__ prevKs, int* __restrict__ nextYs, int t) {
    __shared__ double wredd[4];
    __shared__ double lse_lds[BEAM];
    __shared__ double sc_lds[BEAM];
    __shared__ double bwv[4];
    __shared__ unsigned bwf[4];
    __shared__ unsigned winf_s;
    __shared__ int pk_lds[BEAM];
    __shared__ int ny_lds[BEAM];
    __shared__ double val_lds[BEAM];
    int tid = threadIdx.x;
    int wv = tid >> 6, lane = tid & 63;
    if (tid < BEAM) sc_lds[tid] = scores[tid];
    for (int b = 0; b < BEAM; b++) {
        double s = 0.0;
        for (int j = tid; j < npart; j += 256) s += partials[j * BEAM + b];
        for (int o = 32; o; o >>= 1) s += __shfl_down(s, o);
        if (lane == 0) wredd[wv] = s;
        __syncthreads();
        if (tid == 0) lse_lds[b] = log(wredd[0] + wredd[1] + wredd[2] + wredd[3]);
        __syncthreads();
    }
    double   cv[13];
    unsigned cf[13];
#pragma unroll
    for (int e = 0; e < 13; e++) {
        int c = e * 256 + tid;
        cv[e] = -1.0e308; cf[e] = 0xFFFFFFFFu;
        if (c < 3200) {
            u64 k0 = cands[c];
            if (k0) {
                int r = c / 320;
                float v = unfkey((unsigned)(k0 >> 32));
                unsigned p = ~((unsigned)k0);
                double v2;
                if (t == 0) v2 = (r == 0) ? ((double)v - lse_lds[0]) : (double)NEGF;
                else        v2 = ((double)v - lse_lds[r]) + sc_lds[r];
                cv[e] = v2;
                cf[e] = (unsigned)r * PV + p;
            }
        }
    }
    for (int round = 0; round < BEAM; round++) {
        double bv = -1.0e308; unsigned bf = 0xFFFFFFFFu;
#pragma unroll
        for (int e = 0; e < 13; e++) {
            if (cv[e] > bv || (cv[e] == bv && cf[e] < bf)) { bv = cv[e]; bf = cf[e]; }
        }
        for (int o = 32; o; o >>= 1) {
            double ov = __shfl_down(bv, o);
            unsigned of = __shfl_down(bf, o);
            if (ov > bv || (ov == bv && of < bf)) { bv = ov; bf = of; }
        }
        if (lane == 0) { bwv[wv] = bv; bwf[wv] = bf; }
        __syncthreads();
        if (tid == 0) {
            double xv = bwv[0]; unsigned xf = bwf[0];
            for (int i = 1; i < 4; i++) {
                if (bwv[i] > xv || (bwv[i] == xv && bwf[i] < xf)) { xv = bwv[i]; xf = bwf[i]; }
            }
            winf_s = xf;
            int pk = (int)(xf / PV);
            int ny = (int)(xf - (unsigned)pk * PV);
            pk_lds[round] = pk; ny_lds[round] = ny; val_lds[round] = xv;
        }
        __syncthreads();
        unsigned wff = winf_s;
#pragma unroll
        for (int e = 0; e < 13; e++) {
            if (cf[e] == wff) { cv[e] = -1.0e308; cf[e] = 0xFFFFFFFFu; }
        }
    }
    if (tid < BEAM) {
        scores[tid] = val_lds[tid];
        tokens[tid] = ny_lds[tid];
        prevKs[t * BEAM + tid] = pk_lds[tid];
        nextYs[t * BEAM + tid] = ny_lds[tid];
    }
    __syncthreads();
    for (int idx = tid; idx < BEAM * HD; idx += 256) {
        int i = idx / HD, j = idx - i * HD;
        h_ws[idx] = h2_ws[pk_lds[i] * HD + j];
        c_ws[idx] = c2_ws[pk_lds[i] * HD + j];
    }
}

__global__ void k_traceback(const int* __restrict__ prevKs, const int* __restrict__ nextYs,
                            int* __restrict__ out) {
    int k = threadIdx.x;
    if (k >= BEAM) return;
    int cur = k;
    for (int t = MAXLEN - 1; t >= 0; t--) {
        out[k * MAXLEN + t] = nextYs[t * BEAM + cur];
        cur = prevKs[t * BEAM + cur];
    }
}

extern "C" void kernel_launch(void* const* d_in, const int* in_sizes, int n_in,
                              void* d_out, int out_size, void* d_ws, size_t ws_size,
                              hipStream_t stream) {
    const int*   g_seq  = (const int*)  d_in[0];
    const float* encEmb = (const float*)d_in[1];
    const float* encWih = (const float*)d_in[2];
    const float* encWhh = (const float*)d_in[3];
    const float* encBih = (const float*)d_in[4];
    const float* encBhh = (const float*)d_in[5];
    const float* decEmb = (const float*)d_in[6];
    const float* decWih = (const float*)d_in[7];
    const float* decWhh = (const float*)d_in[8];
    const float* decBih = (const float*)d_in[9];
    const float* decBhh = (const float*)d_in[10];
    const float* attnW  = (const float*)d_in[11];
    const float* outW   = (const float*)d_in[12];
    const float* outB   = (const float*)d_in[13];

    float* ws = (float*)d_ws;
    float*  X     = ws + OFF_X;
    float*  cbuf  = ws + OFF_CBUF;
    float*  gbuf  = ws + OFF_GBUF;
    float*  ctx   = ws + OFF_CTX;
    float*  dh    = ws + OFF_DH;
    float*  dc    = ws + OFF_DC;
    float*  dg    = ws + OFF_DG;
    float*  h2    = ws + OFF_H2;
    float*  c2    = ws + OFF_C2;
    float*  o     = ws + OFF_O;
    double* sc    = (double*)(ws + OFF_SCD);
    int*    tok   = (int*)(ws + OFF_TOK);
    int*    prevK = (int*)(ws + OFF_PREVK);
    int*    nextY = (int*)(ws + OFF_NEXTY);
    int*    bar   = (int*)(ws + OFF_BAR);
    float*  outW4 = ws + OFF_OWT;

    bool bigws = (ws_size >= NEED_T_BYTES);

    k_prep<<<16000, 256, 0, stream>>>(g_seq, encEmb, encWih, encBih, encBhh, X, cbuf, bar);
    if (bigws) k_transpose4<<<dim3(782, 8), 256, 0, stream>>>(outW, outW4);

    if (bigws) {
        MegaA a;
        a.encWhh = encWhh; a.X = X;
        a.gbuf = gbuf; a.cbuf = cbuf; a.ctx = ctx;
        a.decEmb = decEmb; a.decWih = decWih; a.decWhh = decWhh;
        a.decBih = decBih; a.decBhh = decBhh; a.attnW = attnW;
        a.outW4 = outW4; a.outB = outB;
        a.dh = dh; a.dc = dc; a.dg = dg; a.h2w = h2; a.c2w = c2; a.ow = o;
        a.sc = sc; a.part = (double*)(ws + OFF_PARTD); a.lse = (double*)(ws + OFF_LSE);
        a.tok = tok; a.prevK = prevK; a.nextY = nextY;
        a.cand = (u64*)(ws + OFF_CAND); a.rc = (u64*)(ws + OFF_RC);
        a.outTok = (int*)d_out; a.bar = bar;
        k_mega2<<<GRID2, 256, 0, stream>>>(a);
    } else {
        double* part  = (double*)(ws + OFF_PARTF);
        u64*    cand  = (u64*)(ws + OFF_CANDF);
        float*  logits = ws + OFF_LOG;
        for (int t = 0; t <= SLEN; t++)
            k_enc<<<250, 256, 0, stream>>>(encWhh, X, gbuf, cbuf, ctx, dh, dc, sc, tok, t);
        const int npart = 782;
        for (int t = 0; t < MAXLEN; t++) {
            k_gates<<<125, 1024, 0, stream>>>(decEmb, decWih, decWhh, decBih, decBhh, tok, dh, dg);
            k_attn_oproj<<<125, 256, 0, stream>>>(dg, dc, ctx, attnW, h2, c2, o);
            k_logits_f<<<782, 256, 0, stream>>>(outW, outB, o, logits, part);
            k_topk_row<<<320, 256, 0, stream>>>(logits, cand);
            k_merge<<<1, 256, 0, stream>>>(part, npart, cand, sc, tok, h2, c2, dh, dc, prevK, nextY, t);
        }
        k_traceback<<<1, 64, 0, stream>>>(prevK, nextY, (int*)d_out);
    }
}

// Round 10
// 5725.940 us; speedup vs baseline: 2.2597x; 1.3936x over previous
//
#include <hip/hip_runtime.h>
#include <math.h>

#define BEAM   10
#define MAXLEN 32
#define SLEN   32
#define HD     500
#define ED     500
#define G4     2000
#define PV     50000
#define NEGF   (-1e30f)
#define NEGD   (-1.0e30)

#define NSTRIP 196               // logits strip blocks (196*256 >= 50000)
#define CPR    (NSTRIP * BEAM)   // 1960 candidates per row

typedef unsigned long long u64;

// ---------------- ws layout (float element offsets) ----------------
#define OFF_X      0
#define OFF_CBUF   64000
#define OFF_GBUF   65000
#define OFF_CTX    69000
#define OFF_DH     85000
#define OFF_DC     90000
#define OFF_DG     95000
#define OFF_H2     115000
#define OFF_C2     120000
#define OFF_O      125000
#define OFF_SCD    135000   // double[20] score ping-pong (40 float slots)
#define OFF_TOK    135040   // 10 ints (fallback path)
#define OFF_PREVK  135060   // 320 ints
#define OFF_NEXTY  135380   // 320 ints
// fallback-path regions (R4 layout)
#define OFF_PARTF  136000   // double[7820]
#define OFF_CANDF  152000   // u64[3200]
#define OFF_LOG    160000   // fallback logits buffer
// new-path regions (inside fallback LOG region; paths exclusive)
#define OFF_PARTD  160284   // double[1960]
#define OFF_CAND   165604   // u64[19600]
#define OFF_OWT    660000   // float4-blocked transposed out_W (100 MB)
#define NEED_T_BYTES ((size_t)(OFF_OWT + (size_t)HD * PV) * 4)

__device__ __forceinline__ float sigf(float x) { return 1.f / (1.f + expf(-x)); }

__device__ __forceinline__ unsigned fkey(float f) {
    unsigned u = __float_as_uint(f);
    return (u & 0x80000000u) ? ~u : (u | 0x80000000u);
}
__device__ __forceinline__ float unfkey(unsigned k) {
    unsigned u = (k & 0x80000000u) ? (k & 0x7fffffffu) : ~k;
    return __uint_as_float(u);
}

// ---------------- prep ----------------
__global__ void k_prep(const int* __restrict__ g_seq, const float* __restrict__ enc_emb,
                       const float* __restrict__ Wih, const float* __restrict__ bih,
                       const float* __restrict__ bhh, float* __restrict__ X,
                       float* __restrict__ cbuf0) {
    if (blockIdx.x == 0) {
        for (int j = threadIdx.x; j < HD; j += 256) cbuf0[j] = 0.f;
    }
    int wv = (blockIdx.x * blockDim.x + threadIdx.x) >> 6;
    int lane = threadIdx.x & 63;
    if (wv >= SLEN * G4) return;
    int t = wv / G4, r = wv - t * G4;
    const float* emb = enc_emb + (size_t)g_seq[t] * ED;
    const float* w = Wih + (size_t)r * ED;
    float acc = 0.f;
    for (int ki = 0; ki < 8; ki++) { int k = ki * 64 + lane; if (k < ED) acc += emb[k] * w[k]; }
    for (int o = 32; o; o >>= 1) acc += __shfl_down(acc, o);
    if (lane == 0) X[t * G4 + r] = acc + bih[r] + bhh[r];
}

// ---------------- out_W blocked transpose ----------------
__global__ void k_transpose4(const float* __restrict__ outW, float* __restrict__ outW4) {
    __shared__ float t_lds[64][65];
    int tid = threadIdx.x;
    int pbase = blockIdx.x * 64, kbase = blockIdx.y * 64;
    for (int e = 0; e < 16; e++) {
        int idx = e * 256 + tid; int pl = idx >> 6, kl = idx & 63;
        int pp = pbase + pl, kk = kbase + kl;
        t_lds[pl][kl] = (pp < PV && kk < HD) ? outW[(size_t)pp * HD + kk] : 0.f;
    }
    __syncthreads();
    for (int e = 0; e < 4; e++) {
        int idx = e * 256 + tid;
        int pl = idx & 63, kb = idx >> 6;
        int pp = pbase + pl;
        int kglob = kbase + kb * 4;
        if (pp < PV && kglob < HD) {
            float4 v;
            v.x = t_lds[pl][kb * 4 + 0];
            v.y = t_lds[pl][kb * 4 + 1];
            v.z = t_lds[pl][kb * 4 + 2];
            v.w = t_lds[pl][kb * 4 + 3];
            *(float4*)(outW4 + ((size_t)(kbase / 4 + kb) * PV + pp) * 4) = v;
        }
    }
}

// ---------------- encoder step (R4-validated) ----------------
__global__ void k_enc(const float* __restrict__ Whh, const float* __restrict__ X,
                      float* __restrict__ gbuf, float* __restrict__ cbuf,
                      float* __restrict__ context, float* __restrict__ dec_h,
                      float* __restrict__ dec_c, double* __restrict__ scores,
                      int* __restrict__ tokens, int t) {
    __shared__ float h_lds[HD];
    const float* gprev = gbuf + ((t + 1) & 1) * G4;
    float*       gcur  = gbuf + (t & 1) * G4;
    const float* cprev = cbuf + ((t + 1) & 1) * HD;
    float*       ccur  = cbuf + (t & 1) * HD;
    int tid = threadIdx.x;
    if (t > 0) {
        for (int j = tid; j < HD; j += 256) {
            float gi = gprev[j], gf = gprev[HD + j], gg = gprev[2 * HD + j], go = gprev[3 * HD + j];
            float c = sigf(gf) * cprev[j] + sigf(gi) * tanhf(gg);
            float h = sigf(go) * tanhf(c);
            h_lds[j] = h;
            if (blockIdx.x == 0) {
                ccur[j] = c;
                context[(t - 1) * HD + j] = h;
                if (t == SLEN) {
                    for (int b = 0; b < BEAM; b++) { dec_h[b * HD + j] = h; dec_c[b * HD + j] = c; }
                }
            }
        }
    } else {
        for (int j = tid; j < HD; j += 256) h_lds[j] = 0.f;
    }
    if (t == SLEN && blockIdx.x == 0 && tid == 0) {
        for (int b = 0; b < BEAM; b++) scores[b] = 0.0;
        tokens[0] = 2; for (int b = 1; b < BEAM; b++) tokens[b] = 1;
    }
    __syncthreads();
    if (t < SLEN) {
        int wv = blockIdx.x * 4 + (tid >> 6), lane = tid & 63;
        for (int r = wv; r < G4; r += 1000) {
            const float* w = Whh + (size_t)r * HD;
            float acc = 0.f;
            for (int ki = 0; ki < 8; ki++) { int k = ki * 64 + lane; if (k < HD) acc += h_lds[k] * w[k]; }
            for (int o = 32; o; o >>= 1) acc += __shfl_down(acc, o);
            if (lane == 0) gcur[r] = X[t * G4 + r] + acc;
        }
    }
}

// ================= redundant merge (device fn, 512 threads) =================
struct MrgSm {
    double lse[BEAM]; double scl[BEAM];
    u64 rc[BEAM * BEAM];
    double gbv[8]; unsigned gbf[8]; unsigned winf;
    int pk[BEAM]; int ny[BEAM]; double val[BEAM];
};

// Performs beam-merge step m: per-row top10 over strip candidates (u64 keys,
// offset-invariant within a row; R8/R9-validated) then fp64 global merge with
// flat-index tie-break (R3+-validated semantics). Results in M->pk/ny/val.
__device__ __forceinline__ void do_merge(MrgSm* M, const double* __restrict__ part,
                                         const u64* __restrict__ cand,
                                         const double* __restrict__ sc_in,
                                         int m, int tid) {
    int wv = tid >> 6, lane = tid & 63;
    if (tid < BEAM) M->scl[tid] = sc_in[tid];
    // per-row lse (fp64)
    for (int r = wv; r < BEAM; r += 8) {
        double s = 0.0;
        for (int i = lane; i < NSTRIP; i += 64) s += part[r * NSTRIP + i];
        for (int o = 32; o; o >>= 1) s += __shfl_down(s, o);
        if (lane == 0) M->lse[r] = log(s);
    }
    // per-row top-10 over 1960 strip candidates (wave tournament, u64 keys)
    for (int r = wv; r < BEAM; r += 8) {
        u64 kk[31];
        int n = 0;
        for (int i = lane; i < CPR; i += 64) kk[n++] = cand[(size_t)r * CPR + i];
        for (; n < 31; ++n) kk[n] = 0ull;
        for (int round = 0; round < BEAM; ++round) {
            u64 mx = 0ull;
#pragma unroll
            for (int e = 0; e < 31; e++) if (kk[e] > mx) mx = kk[e];
            for (int o = 32; o; o >>= 1) { u64 t2 = __shfl_down(mx, o); if (t2 > mx) mx = t2; }
            u64 win = __shfl(mx, 0);
#pragma unroll
            for (int e = 0; e < 31; e++) if (kk[e] == win) kk[e] = 0ull;
            if (lane == 0) M->rc[r * BEAM + round] = win;
        }
    }
    __syncthreads();
    // global merge over 100 candidates (fp64 value, flat-index tiebreak)
    double cv = -1.0e308; unsigned cf = 0xFFFFFFFFu;
    if (tid < BEAM * BEAM) {
        u64 k0 = M->rc[tid];
        if (k0) {
            int r2 = tid / BEAM;
            float v = unfkey((unsigned)(k0 >> 32));
            unsigned p = ~((unsigned)k0);
            double v2;
            if (m == 0) v2 = (r2 == 0) ? ((double)v - M->lse[0]) : NEGD;
            else        v2 = ((double)v - M->lse[r2]) + M->scl[r2];
            cv = v2; cf = (unsigned)r2 * PV + p;
        }
    }
    for (int round = 0; round < BEAM; ++round) {
        double bv = cv; unsigned bf = cf;
        for (int o = 32; o; o >>= 1) {
            double ov = __shfl_down(bv, o);
            unsigned of = __shfl_down(bf, o);
            if (ov > bv || (ov == bv && of < bf)) { bv = ov; bf = of; }
        }
        if (lane == 0) { M->gbv[wv] = bv; M->gbf[wv] = bf; }
        __syncthreads();
        if (tid == 0) {
            double xv = M->gbv[0]; unsigned xf = M->gbf[0];
            for (int i = 1; i < 8; i++) {
                if (M->gbv[i] > xv || (M->gbv[i] == xv && M->gbf[i] < xf)) { xv = M->gbv[i]; xf = M->gbf[i]; }
            }
            M->winf = xf;
            int pk = (int)(xf / PV);
            int ny = (int)(xf - (unsigned)pk * PV);
            M->pk[round] = pk; M->ny[round] = ny; M->val[round] = xv;
        }
        __syncthreads();
        if (cf == M->winf) { cv = -1.0e308; cf = 0xFFFFFFFFu; }
        __syncthreads();
    }
}

// ================= fused merge(t-1) + gates (125 x 512) =================
__global__ __launch_bounds__(512) void k_gates_m(
        const float* __restrict__ decEmb, const float* __restrict__ Wih,
        const float* __restrict__ Whh, const float* __restrict__ bih,
        const float* __restrict__ bhh,
        const double* __restrict__ part, const u64* __restrict__ cand,
        const double* __restrict__ sc_in, double* __restrict__ sc_out,
        const float* __restrict__ h2w, const float* __restrict__ c2w,
        float* __restrict__ dc, const float* __restrict__ dh0,
        int* __restrict__ prevK, int* __restrict__ nextY,
        float* __restrict__ gates, int t) {
    __shared__ float e_lds[BEAM * ED];
    __shared__ float h_lds[BEAM * HD];
    __shared__ MrgSm M;
    int tid = threadIdx.x, bid = blockIdx.x;
    int wv = tid >> 6, lane = tid & 63;

    if (t > 0) {
        int m = t - 1;
        do_merge(&M, part, cand, sc_in, m, tid);
        if (tid < BEAM && bid == 0) {
            sc_out[tid] = M.val[tid];
            prevK[m * BEAM + tid] = M.pk[tid];
            nextY[m * BEAM + tid] = M.ny[tid];
        }
        __syncthreads();
        for (int idx = tid; idx < BEAM * HD; idx += 512) {
            int b = idx / HD, j = idx - b * HD;
            h_lds[idx] = h2w[M.pk[b] * HD + j];
            e_lds[idx] = decEmb[(size_t)M.ny[b] * ED + j];
            if (bid == 0) dc[idx] = c2w[M.pk[b] * HD + j];
        }
    } else {
        for (int idx = tid; idx < BEAM * HD; idx += 512) {
            int b = idx / HD, j = idx - b * HD;
            int tk = (b == 0) ? 2 : 1;
            h_lds[idx] = dh0[idx];
            e_lds[idx] = decEmb[(size_t)tk * ED + j];
        }
    }
    __syncthreads();

    // gates: 16 rows/block, 2 rows/wave (per-row math identical to R4 k_gates)
    for (int rr = 0; rr < 2; ++rr) {
        int r = bid * 16 + wv * 2 + rr;
        const float* wi = Wih + (size_t)r * ED;
        const float* wh = Whh + (size_t)r * HD;
        float acc[BEAM];
#pragma unroll
        for (int b = 0; b < BEAM; b++) acc[b] = 0.f;
        for (int ki = 0; ki < 8; ki++) {
            int k = ki * 64 + lane;
            if (k < ED) {
                float w = wi[k];
#pragma unroll
                for (int b = 0; b < BEAM; b++) acc[b] += w * e_lds[b * ED + k];
            }
        }
        for (int ki = 0; ki < 8; ki++) {
            int k = ki * 64 + lane;
            if (k < HD) {
                float w = wh[k];
#pragma unroll
                for (int b = 0; b < BEAM; b++) acc[b] += w * h_lds[b * HD + k];
            }
        }
#pragma unroll
        for (int b = 0; b < BEAM; b++) {
            float v = acc[b];
            for (int o = 32; o; o >>= 1) v += __shfl_down(v, o);
            acc[b] = v;
        }
        if (lane == 0) {
            float bb = bih[r] + bhh[r];
#pragma unroll
            for (int b = 0; b < BEAM; b++) gates[b * G4 + r] = acc[b] + bb;
        }
    }
}

// ---------------- attn + oproj (125 x 256, R4-validated) ----------------
__global__ __launch_bounds__(256) void k_attn_oproj(
        const float* __restrict__ gates, const float* __restrict__ c_ws,
        const float* __restrict__ context, const float* __restrict__ attnW,
        float* __restrict__ h2_ws, float* __restrict__ c2_ws, float* __restrict__ o_ws) {
    __shared__ float h2_lds[BEAM * HD];
    __shared__ float wctx_lds[BEAM * HD];
    __shared__ float s_lds[BEAM * SLEN];
    __shared__ float a_lds[BEAM * SLEN];
    int tid = threadIdx.x;
    int wv = tid >> 6, lane = tid & 63;
    for (int idx = tid; idx < BEAM * HD; idx += 256) {
        int b = idx / HD, j = idx - b * HD;
        float gi = gates[b * G4 + j], gf = gates[b * G4 + HD + j];
        float gg = gates[b * G4 + 2 * HD + j], go = gates[b * G4 + 3 * HD + j];
        float c = sigf(gf) * c_ws[idx] + sigf(gi) * tanhf(gg);
        float h2 = sigf(go) * tanhf(c);
        h2_lds[idx] = h2;
        if (blockIdx.x == 0) { c2_ws[idx] = c; h2_ws[idx] = h2; }
    }
    __syncthreads();
    for (int si = 0; si < 8; ++si) {
        int s = wv + 4 * si;
        float acc[BEAM];
#pragma unroll
        for (int b = 0; b < BEAM; b++) acc[b] = 0.f;
        for (int ki = 0; ki < 8; ki++) {
            int k = ki * 64 + lane;
            if (k < HD) {
                float c = context[s * HD + k];
#pragma unroll
                for (int b = 0; b < BEAM; b++) acc[b] += c * h2_lds[b * HD + k];
            }
        }
#pragma unroll
        for (int b = 0; b < BEAM; b++) {
            float v = acc[b];
            for (int o = 32; o; o >>= 1) v += __shfl_down(v, o);
            if (lane == 0) s_lds[b * SLEN + s] = v;
        }
    }
    __syncthreads();
    if (wv == 0) {
        for (int b = 0; b < BEAM; ++b) {
            float v = (lane < SLEN) ? s_lds[b * SLEN + lane] : -INFINITY;
            float m = v;
            for (int o = 32; o; o >>= 1) m = fmaxf(m, __shfl_xor(m, o));
            float e = (lane < SLEN) ? expf(v - m) : 0.f;
            float sum = e;
            for (int o = 32; o; o >>= 1) sum += __shfl_xor(sum, o);
            if (lane < SLEN) a_lds[b * SLEN + lane] = e / sum;
        }
    }
    __syncthreads();
    {
        float w0[BEAM], w1[BEAM];
#pragma unroll
        for (int b = 0; b < BEAM; b++) { w0[b] = 0.f; w1[b] = 0.f; }
        int j0 = tid, j1 = tid + 256;
        for (int s = 0; s < SLEN; ++s) {
            float c0 = (j0 < HD) ? context[s * HD + j0] : 0.f;
            float c1 = (j1 < HD) ? context[s * HD + j1] : 0.f;
#pragma unroll
            for (int b = 0; b < BEAM; b++) {
                float a = a_lds[b * SLEN + s];
                w0[b] += a * c0; w1[b] += a * c1;
            }
        }
#pragma unroll
        for (int b = 0; b < BEAM; b++) {
            if (j0 < HD) wctx_lds[b * HD + j0] = w0[b];
            if (j1 < HD) wctx_lds[b * HD + j1] = w1[b];
        }
    }
    __syncthreads();
    int j = blockIdx.x * 4 + wv;
    const float* w = attnW + (size_t)j * 1000;
    float acc[BEAM];
#pragma unroll
    for (int b = 0; b < BEAM; b++) acc[b] = 0.f;
    for (int ki = 0; ki < 16; ki++) {
        int k = ki * 64 + lane;
        if (k < 1000) {
            float wk = w[k];
#pragma unroll
            for (int b = 0; b < BEAM; b++) {
                float h = (k < HD) ? h2_lds[b * HD + k] : wctx_lds[b * HD + k - HD];
                acc[b] += wk * h;
            }
        }
    }
#pragma unroll
    for (int b = 0; b < BEAM; b++) {
        float v = acc[b];
        for (int o = 32; o; o >>= 1) v += __shfl_down(v, o);
        acc[b] = v;
    }
    if (lane == 0) {
#pragma unroll
        for (int b = 0; b < BEAM; b++) o_ws[b * HD + j] = tanhf(acc[b]);
    }
}

// ---------------- fused logits + strip top-10 + fp64 sumexp (196 x 256) ----------------
__global__ __launch_bounds__(256) void k_logits_topk(
        const float* __restrict__ outW4, const float* __restrict__ outB,
        const float* __restrict__ o_ws, u64* __restrict__ cand,
        double* __restrict__ part) {
    __shared__ __align__(16) char sm[40960];
    float4* o4 = (float4*)sm;
    int tid = threadIdx.x, bid = blockIdx.x;
    int wv = tid >> 6, lane = tid & 63;
    for (int idx = tid; idx < BEAM * 125; idx += 256) {
        int b = idx / 125, kb = idx - b * 125;
        o4[idx] = *(const float4*)(o_ws + b * HD + kb * 4);
    }
    __syncthreads();
    int p = bid * 256 + tid;
    bool valid = (p < PV);
    int pc = valid ? p : (PV - 1);
    float lg[BEAM];
    {
        float acc[BEAM];
#pragma unroll
        for (int b = 0; b < BEAM; b++) acc[b] = 0.f;
        const float4* wp = (const float4*)outW4;
        for (int kb = 0; kb < 125; ++kb) {
            float4 w = wp[(size_t)kb * PV + pc];
#pragma unroll
            for (int b = 0; b < BEAM; b++) {
                float4 o = o4[b * 125 + kb];
                acc[b] += w.x * o.x + w.y * o.y + w.z * o.z + w.w * o.w;
            }
        }
        float ob = outB[pc];
#pragma unroll
        for (int b = 0; b < BEAM; b++) lg[b] = acc[b] + ob;
    }
    // fp64 partial sumexp per row
    double* pd = (double*)(sm + 20480);
#pragma unroll
    for (int b = 0; b < BEAM; b++) pd[b * 256 + tid] = valid ? exp((double)lg[b]) : 0.0;
    __syncthreads();
    for (int r = wv; r < BEAM; r += 4) {
        double s = pd[r * 256 + lane] + pd[r * 256 + 64 + lane]
                 + pd[r * 256 + 128 + lane] + pd[r * 256 + 192 + lane];
        for (int o = 32; o; o >>= 1) s += __shfl_down(s, o);
        if (lane == 0) part[r * NSTRIP + bid] = s;
    }
    __syncthreads();
    // per-strip per-row top-10 (u64 keys)
    u64* kl = (u64*)(sm + 20480);
#pragma unroll
    for (int b = 0; b < BEAM; b++)
        kl[b * 256 + tid] = valid ? (((u64)fkey(lg[b]) << 32) | (unsigned)(~(unsigned)p)) : 0ull;
    __syncthreads();
    for (int r = wv; r < BEAM; r += 4) {
        u64 kk[4];
#pragma unroll
        for (int j = 0; j < 4; j++) kk[j] = kl[r * 256 + j * 64 + lane];
        for (int round = 0; round < BEAM; round++) {
            u64 m = kk[0];
            if (kk[1] > m) m = kk[1];
            if (kk[2] > m) m = kk[2];
            if (kk[3] > m) m = kk[3];
            for (int o = 32; o; o >>= 1) {
                u64 t2 = __shfl_down(m, o);
                if (t2 > m) m = t2;
            }
            u64 win = __shfl(m, 0);
#pragma unroll
            for (int j = 0; j < 4; j++) if (kk[j] == win) kk[j] = 0ull;
            if (lane == 0) cand[(size_t)r * CPR + bid * 10 + round] = win;
        }
    }
}

// ---------------- final merge(31) + traceback (1 x 512) ----------------
__global__ __launch_bounds__(512) void k_final(
        const double* __restrict__ part, const u64* __restrict__ cand,
        const double* __restrict__ sc_in,
        int* __restrict__ prevK, int* __restrict__ nextY, int* __restrict__ out) {
    __shared__ MrgSm M;
    int tid = threadIdx.x;
    do_merge(&M, part, cand, sc_in, MAXLEN - 1, tid);
    if (tid < BEAM) {
        prevK[(MAXLEN - 1) * BEAM + tid] = M.pk[tid];
        nextY[(MAXLEN - 1) * BEAM + tid] = M.ny[tid];
    }
    __syncthreads();
    if (tid < BEAM) {
        int cur = tid;
        for (int tt = MAXLEN - 1; tt >= 0; tt--) {
            out[tid * MAXLEN + tt] = nextY[tt * BEAM + cur];
            cur = prevK[tt * BEAM + cur];
        }
    }
}

// ======================================================================
// R4 fallback kernels (used only when ws is too small for transposed W)
// ======================================================================
__global__ __launch_bounds__(1024) void k_gates(
        const float* __restrict__ dec_emb, const float* __restrict__ Wih,
        const float* __restrict__ Whh, const float* __restrict__ bih,
        const float* __restrict__ bhh, const int* __restrict__ tokens,
        const float* __restrict__ h_ws, float* __restrict__ gates) {
    __shared__ float e_lds[BEAM * ED];
    __shared__ float h_lds[BEAM * HD];
    int tid = threadIdx.x;
    for (int idx = tid; idx < BEAM * ED; idx += 1024) {
        int b = idx / ED, k = idx - b * ED;
        e_lds[idx] = dec_emb[(size_t)tokens[b] * ED + k];
        h_lds[idx] = h_ws[idx];
    }
    __syncthreads();
    int wv = tid >> 6, lane = tid & 63;
    int r = blockIdx.x * 16 + wv;
    const float* wi = Wih + (size_t)r * ED;
    const float* wh = Whh + (size_t)r * HD;
    float acc[BEAM];
#pragma unroll
    for (int b = 0; b < BEAM; b++) acc[b] = 0.f;
    for (int ki = 0; ki < 8; ki++) {
        int k = ki * 64 + lane;
        if (k < ED) {
            float w = wi[k];
#pragma unroll
            for (int b = 0; b < BEAM; b++) acc[b] += w * e_lds[b * ED + k];
        }
    }
    for (int ki = 0; ki < 8; ki++) {
        int k = ki * 64 + lane;
        if (k < HD) {
            float w = wh[k];
#pragma unroll
            for (int b = 0; b < BEAM; b++) acc[b] += w * h_lds[b * HD + k];
        }
    }
#pragma unroll
    for (int b = 0; b < BEAM; b++) {
        float v = acc[b];
        for (int o = 32; o; o >>= 1) v += __shfl_down(v, o);
        acc[b] = v;
    }
    if (lane == 0) {
        float bb = bih[r] + bhh[r];
#pragma unroll
        for (int b = 0; b < BEAM; b++) gates[b * G4 + r] = acc[b] + bb;
    }
}

__global__ void k_logits_f(const float* __restrict__ outW, const float* __restrict__ outB,
                           const float* __restrict__ o_ws, float* __restrict__ logits,
                           double* __restrict__ partials) {
    __shared__ float o_lds[BEAM * HD];
    __shared__ double ered[4][BEAM];
    int tid = threadIdx.x;
    for (int idx = tid; idx < BEAM * HD; idx += 256) o_lds[idx] = o_ws[idx];
    __syncthreads();
    int wv = tid >> 6, lane = tid & 63;
    int w = blockIdx.x * 4 + wv;
    double esum = 0.0;
    for (int pi = 0; pi < 16; pi++) {
        int p = w * 16 + pi;
        if (p >= PV) break;
        const float* wr = outW + (size_t)p * HD;
        float acc[BEAM];
#pragma unroll
        for (int b = 0; b < BEAM; b++) acc[b] = 0.f;
        for (int ki = 0; ki < 8; ki++) {
            int k = ki * 64 + lane;
            if (k < HD) {
                float x = wr[k];
#pragma unroll
                for (int b = 0; b < BEAM; b++) acc[b] += x * o_lds[b * HD + k];
            }
        }
#pragma unroll
        for (int b = 0; b < BEAM; b++)
            for (int o = 32; o; o >>= 1) acc[b] += __shfl_xor(acc[b], o);
        if (lane < BEAM) {
            float lg = 0.f;
#pragma unroll
            for (int b = 0; b < BEAM; b++) if (lane == b) lg = acc[b];
            lg += outB[p];
            logits[(size_t)lane * PV + p] = lg;
            esum += exp((double)lg);
        }
    }
    if (lane < BEAM) ered[wv][lane] = esum;
    __syncthreads();
    if (tid < BEAM) partials[blockIdx.x * BEAM + tid] =
        ered[0][tid] + ered[1][tid] + ered[2][tid] + ered[3][tid];
}

__global__ __launch_bounds__(256) void k_topk_row(const float* __restrict__ logits,
                                                  u64* __restrict__ cands) {
    const int CH = 1563;
    int r = blockIdx.x >> 5, ci = blockIdx.x & 31;
    int base = ci * CH;
    int tid = threadIdx.x;
    int wv = tid >> 6, lane = tid & 63;
    u64 key[7];
#pragma unroll
    for (int e = 0; e < 7; e++) {
        int p = base + e * 256 + tid;
        key[e] = 0ull;
        if (p < base + CH && p < PV) {
            float v = logits[(size_t)r * PV + p];
            key[e] = ((u64)fkey(v) << 32) | (unsigned)(~(unsigned)p);
        }
    }
    __shared__ u64 wred[4];
    __shared__ u64 winlds;
    for (int round = 0; round < BEAM; round++) {
        u64 mx = 0ull;
#pragma unroll
        for (int e = 0; e < 7; e++) if (key[e] > mx) mx = key[e];
        for (int o = 32; o; o >>= 1) {
            u64 other = __shfl_down(mx, o);
            if (other > mx) mx = other;
        }
        if (lane == 0) wred[wv] = mx;
        __syncthreads();
        if (tid == 0) {
            u64 wn = wred[0];
            for (int i = 1; i < 4; i++) if (wred[i] > wn) wn = wred[i];
            winlds = wn;
            cands[blockIdx.x * BEAM + round] = wn;
        }
        __syncthreads();
        u64 win = winlds;
#pragma unroll
        for (int e = 0; e < 7; e++) if (key[e] == win) key[e] = 0ull;
    }
}

__global__ __launch_bounds__(256) void k_merge(
        const double* __restrict__ partials, int npart,
        const u64* __restrict__ cands,
        double* __restrict__ scores, int* __restrict__ tokens,
        const float* __restrict__ h2_ws, const float* __restrict__ c2_ws,
        float* __restrict__ h_ws, float* __restrict__ c_ws,
        int* __restrict__ prevKs, int* __restrict__ nextYs, int t) {
    __shared__ double wredd[4];
    __shared__ double lse_lds[BEAM];
    __shared__ double sc_lds[BEAM];
    __shared__ double bwv[4];
    __shared__ unsigned bwf[4];
    __shared__ unsigned winf_s;
    __shared__ int pk_lds[BEAM];
    __shared__ int ny_lds[BEAM];
    __shared__ double val_lds[BEAM];
    int tid = threadIdx.x;
    int wv = tid >> 6, lane = tid & 63;
    if (tid < BEAM) sc_lds[tid] = scores[tid];
    for (int b = 0; b < BEAM; b++) {
        double s = 0.0;
        for (int j = tid; j < npart; j += 256) s += partials[j * BEAM + b];
        for (int o = 32; o; o >>= 1) s += __shfl_down(s, o);
        if (lane == 0) wredd[wv] = s;
        __syncthreads();
        if (tid == 0) lse_lds[b] = log(wredd[0] + wredd[1] + wredd[2] + wredd[3]);
        __syncthreads();
    }
    double   cv[13];
    unsigned cf[13];
#pragma unroll
    for (int e = 0; e < 13; e++) {
        int c = e * 256 + tid;
        cv[e] = -1.0e308; cf[e] = 0xFFFFFFFFu;
        if (c < 3200) {
            u64 k0 = cands[c];
            if (k0) {
                int r = c / 320;
                float v = unfkey((unsigned)(k0 >> 32));
                unsigned p = ~((unsigned)k0);
                double v2;
                if (t == 0) v2 = (r == 0) ? ((double)v - lse_lds[0]) : (double)NEGF;
                else        v2 = ((double)v - lse_lds[r]) + sc_lds[r];
                cv[e] = v2;
                cf[e] = (unsigned)r * PV + p;
            }
        }
    }
    for (int round = 0; round < BEAM; round++) {
        double bv = -1.0e308; unsigned bf = 0xFFFFFFFFu;
#pragma unroll
        for (int e = 0; e < 13; e++) {
            if (cv[e] > bv || (cv[e] == bv && cf[e] < bf)) { bv = cv[e]; bf = cf[e]; }
        }
        for (int o = 32; o; o >>= 1) {
            double ov = __shfl_down(bv, o);
            unsigned of = __shfl_down(bf, o);
            if (ov > bv || (ov == bv && of < bf)) { bv = ov; bf = of; }
        }
        if (lane == 0) { bwv[wv] = bv; bwf[wv] = bf; }
        __syncthreads();
        if (tid == 0) {
            double xv = bwv[0]; unsigned xf = bwf[0];
            for (int i = 1; i < 4; i++) {
                if (bwv[i] > xv || (bwv[i] == xv && bwf[i] < xf)) { xv = bwv[i]; xf = bwf[i]; }
            }
            winf_s = xf;
            int pk = (int)(xf / PV);
            int ny = (int)(xf - (unsigned)pk * PV);
            pk_lds[round] = pk; ny_lds[round] = ny; val_lds[round] = xv;
        }
        __syncthreads();
        unsigned wff = winf_s;
#pragma unroll
        for (int e = 0; e < 13; e++) {
            if (cf[e] == wff) { cv[e] = -1.0e308; cf[e] = 0xFFFFFFFFu; }
        }
    }
    if (tid < BEAM) {
        scores[tid] = val_lds[tid];
        tokens[tid] = ny_lds[tid];
        prevKs[t * BEAM + tid] = pk_lds[tid];
        nextYs[t * BEAM + tid] = ny_lds[tid];
    }
    __syncthreads();
    for (int idx = tid; idx < BEAM * HD; idx += 256) {
        int i = idx / HD, j = idx - i * HD;
        h_ws[idx] = h2_ws[pk_lds[i] * HD + j];
        c_ws[idx] = c2_ws[pk_lds[i] * HD + j];
    }
}

__global__ void k_traceback(const int* __restrict__ prevKs, const int* __restrict__ nextYs,
                            int* __restrict__ out) {
    int k = threadIdx.x;
    if (k >= BEAM) return;
    int cur = k;
    for (int t = MAXLEN - 1; t >= 0; t--) {
        out[k * MAXLEN + t] = nextYs[t * BEAM + cur];
        cur = prevKs[t * BEAM + cur];
    }
}

extern "C" void kernel_launch(void* const* d_in, const int* in_sizes, int n_in,
                              void* d_out, int out_size, void* d_ws, size_t ws_size,
                              hipStream_t stream) {
    const int*   g_seq  = (const int*)  d_in[0];
    const float* encEmb = (const float*)d_in[1];
    const float* encWih = (const float*)d_in[2];
    const float* encWhh = (const float*)d_in[3];
    const float* encBih = (const float*)d_in[4];
    const float* encBhh = (const float*)d_in[5];
    const float* decEmb = (const float*)d_in[6];
    const float* decWih = (const float*)d_in[7];
    const float* decWhh = (const float*)d_in[8];
    const float* decBih = (const float*)d_in[9];
    const float* decBhh = (const float*)d_in[10];
    const float* attnW  = (const float*)d_in[11];
    const float* outW   = (const float*)d_in[12];
    const float* outB   = (const float*)d_in[13];

    float* ws = (float*)d_ws;
    float*  X     = ws + OFF_X;
    float*  cbuf  = ws + OFF_CBUF;
    float*  gbuf  = ws + OFF_GBUF;
    float*  ctx   = ws + OFF_CTX;
    float*  dh    = ws + OFF_DH;
    float*  dc    = ws + OFF_DC;
    float*  dg    = ws + OFF_DG;
    float*  h2    = ws + OFF_H2;
    float*  c2    = ws + OFF_C2;
    float*  o     = ws + OFF_O;
    double* scb   = (double*)(ws + OFF_SCD);   // ping-pong pair of 10 doubles
    int*    tok   = (int*)(ws + OFF_TOK);
    int*    prevK = (int*)(ws + OFF_PREVK);
    int*    nextY = (int*)(ws + OFF_NEXTY);
    float*  outW4 = ws + OFF_OWT;

    bool bigws = (ws_size >= NEED_T_BYTES);

    k_prep<<<16000, 256, 0, stream>>>(g_seq, encEmb, encWih, encBih, encBhh, X, cbuf);
    if (bigws) k_transpose4<<<dim3(782, 8), 256, 0, stream>>>(outW, outW4);

    for (int t = 0; t <= SLEN; t++)
        k_enc<<<250, 256, 0, stream>>>(encWhh, X, gbuf, cbuf, ctx, dh, dc, scb, tok, t);

    if (bigws) {
        double* part = (double*)(ws + OFF_PARTD);
        u64*    cand = (u64*)(ws + OFF_CAND);
        for (int t = 0; t < MAXLEN; t++) {
            int m = t - 1;
            const double* sin = scb + ((m & 1) ? 10 : 0);
            double*       sout = scb + (((m + 1) & 1) ? 10 : 0);
            if (t == 0) { sin = scb; sout = scb + 10; }   // unused at t==0
            k_gates_m<<<125, 512, 0, stream>>>(decEmb, decWih, decWhh, decBih, decBhh,
                                               part, cand, sin, sout,
                                               h2, c2, dc, dh, prevK, nextY, dg, t);
            k_attn_oproj<<<125, 256, 0, stream>>>(dg, dc, ctx, attnW, h2, c2, o);
            k_logits_topk<<<NSTRIP, 256, 0, stream>>>(outW4, outB, o, cand, part);
        }
        int mf = MAXLEN - 1;
        k_final<<<1, 512, 0, stream>>>(part, cand, scb + ((mf & 1) ? 10 : 0),
                                       prevK, nextY, (int*)d_out);
    } else {
        // R4-validated fallback (row-major out_W)
        double* part  = (double*)(ws + OFF_PARTF);
        u64*    cand  = (u64*)(ws + OFF_CANDF);
        float*  logits = ws + OFF_LOG;
        const int npart = 782;
        for (int t = 0; t < MAXLEN; t++) {
            k_gates<<<125, 1024, 0, stream>>>(decEmb, decWih, decWhh, decBih, decBhh, tok, dh, dg);
            k_attn_oproj<<<125, 256, 0, stream>>>(dg, dc, ctx, attnW, h2, c2, o);
            k_logits_f<<<782, 256, 0, stream>>>(outW, outB, o, logits, part);
            k_topk_row<<<320, 256, 0, stream>>>(logits, cand);
            k_merge<<<1, 256, 0, stream>>>(part, npart, cand, scb, tok, h2, c2, dh, dc, prevK, nextY, t);
        }
        k_traceback<<<1, 64, 0, stream>>>(prevK, nextY, (int*)d_out);
    }
}

// Round 11
// 4630.048 us; speedup vs baseline: 2.7946x; 1.2367x over previous
//
#include <hip/hip_runtime.h>
#include <math.h>

#define BEAM   10
#define MAXLEN 32
#define SLEN   32
#define HD     500
#define ED     500
#define G4     2000
#define PV     50000
#define NEGF   (-1e30f)
#define NEGD   (-1.0e30)

#define NSTRIP 196               // logits strip blocks (196*256 >= 50000)
#define CPR    (NSTRIP * BEAM)   // 1960 candidates per row

typedef unsigned long long u64;

// ---------------- ws layout (float element offsets) ----------------
#define OFF_X      0
#define OFF_CBUF   64000
#define OFF_GBUF   65000
#define OFF_CTX    69000
#define OFF_DH     85000
#define OFF_DC     90000
#define OFF_DG     95000
#define OFF_H2     115000
#define OFF_C2     120000
#define OFF_O      125000
#define OFF_SCD    135000   // double[20] score ping-pong (40 float slots)
#define OFF_TOK    135040   // 10 ints (fallback path)
#define OFF_PREVK  135060   // 320 ints
#define OFF_NEXTY  135380   // 320 ints
// fallback-path regions (R4 layout)
#define OFF_PARTF  136000   // double[7820]
#define OFF_CANDF  152000   // u64[3200]
#define OFF_LOG    160000   // fallback logits buffer
// new-path regions (inside fallback LOG region; paths exclusive)
#define OFF_PARTD  160284   // double[1960]
#define OFF_CAND   165604   // u64[19600]
#define OFF_OWT    660000   // float4-blocked transposed out_W (100 MB)
#define NEED_T_BYTES ((size_t)(OFF_OWT + (size_t)HD * PV) * 4)

__device__ __forceinline__ float sigf(float x) { return 1.f / (1.f + expf(-x)); }

__device__ __forceinline__ unsigned fkey(float f) {
    unsigned u = __float_as_uint(f);
    return (u & 0x80000000u) ? ~u : (u | 0x80000000u);
}
__device__ __forceinline__ float unfkey(unsigned k) {
    unsigned u = (k & 0x80000000u) ? (k & 0x7fffffffu) : ~k;
    return __uint_as_float(u);
}

// ---------------- prep ----------------
__global__ void k_prep(const int* __restrict__ g_seq, const float* __restrict__ enc_emb,
                       const float* __restrict__ Wih, const float* __restrict__ bih,
                       const float* __restrict__ bhh, float* __restrict__ X,
                       float* __restrict__ cbuf0) {
    if (blockIdx.x == 0) {
        for (int j = threadIdx.x; j < HD; j += 256) cbuf0[j] = 0.f;
    }
    int wv = (blockIdx.x * blockDim.x + threadIdx.x) >> 6;
    int lane = threadIdx.x & 63;
    if (wv >= SLEN * G4) return;
    int t = wv / G4, r = wv - t * G4;
    const float* emb = enc_emb + (size_t)g_seq[t] * ED;
    const float* w = Wih + (size_t)r * ED;
    float acc = 0.f;
    for (int ki = 0; ki < 8; ki++) { int k = ki * 64 + lane; if (k < ED) acc += emb[k] * w[k]; }
    for (int o = 32; o; o >>= 1) acc += __shfl_down(acc, o);
    if (lane == 0) X[t * G4 + r] = acc + bih[r] + bhh[r];
}

// ---------------- out_W blocked transpose ----------------
__global__ void k_transpose4(const float* __restrict__ outW, float* __restrict__ outW4) {
    __shared__ float t_lds[64][65];
    int tid = threadIdx.x;
    int pbase = blockIdx.x * 64, kbase = blockIdx.y * 64;
    for (int e = 0; e < 16; e++) {
        int idx = e * 256 + tid; int pl = idx >> 6, kl = idx & 63;
        int pp = pbase + pl, kk = kbase + kl;
        t_lds[pl][kl] = (pp < PV && kk < HD) ? outW[(size_t)pp * HD + kk] : 0.f;
    }
    __syncthreads();
    for (int e = 0; e < 4; e++) {
        int idx = e * 256 + tid;
        int pl = idx & 63, kb = idx >> 6;
        int pp = pbase + pl;
        int kglob = kbase + kb * 4;
        if (pp < PV && kglob < HD) {
            float4 v;
            v.x = t_lds[pl][kb * 4 + 0];
            v.y = t_lds[pl][kb * 4 + 1];
            v.z = t_lds[pl][kb * 4 + 2];
            v.w = t_lds[pl][kb * 4 + 3];
            *(float4*)(outW4 + ((size_t)(kbase / 4 + kb) * PV + pp) * 4) = v;
        }
    }
}

// ---------------- encoder step (R4-validated) ----------------
__global__ void k_enc(const float* __restrict__ Whh, const float* __restrict__ X,
                      float* __restrict__ gbuf, float* __restrict__ cbuf,
                      float* __restrict__ context, float* __restrict__ dec_h,
                      float* __restrict__ dec_c, double* __restrict__ scores,
                      int* __restrict__ tokens, int t) {
    __shared__ float h_lds[HD];
    const float* gprev = gbuf + ((t + 1) & 1) * G4;
    float*       gcur  = gbuf + (t & 1) * G4;
    const float* cprev = cbuf + ((t + 1) & 1) * HD;
    float*       ccur  = cbuf + (t & 1) * HD;
    int tid = threadIdx.x;
    if (t > 0) {
        for (int j = tid; j < HD; j += 256) {
            float gi = gprev[j], gf = gprev[HD + j], gg = gprev[2 * HD + j], go = gprev[3 * HD + j];
            float c = sigf(gf) * cprev[j] + sigf(gi) * tanhf(gg);
            float h = sigf(go) * tanhf(c);
            h_lds[j] = h;
            if (blockIdx.x == 0) {
                ccur[j] = c;
                context[(t - 1) * HD + j] = h;
                if (t == SLEN) {
                    for (int b = 0; b < BEAM; b++) { dec_h[b * HD + j] = h; dec_c[b * HD + j] = c; }
                }
            }
        }
    } else {
        for (int j = tid; j < HD; j += 256) h_lds[j] = 0.f;
    }
    if (t == SLEN && blockIdx.x == 0 && tid == 0) {
        for (int b = 0; b < BEAM; b++) scores[b] = 0.0;
        tokens[0] = 2; for (int b = 1; b < BEAM; b++) tokens[b] = 1;
    }
    __syncthreads();
    if (t < SLEN) {
        int wv = blockIdx.x * 4 + (tid >> 6), lane = tid & 63;
        for (int r = wv; r < G4; r += 1000) {
            const float* w = Whh + (size_t)r * HD;
            float acc = 0.f;
            for (int ki = 0; ki < 8; ki++) { int k = ki * 64 + lane; if (k < HD) acc += h_lds[k] * w[k]; }
            for (int o = 32; o; o >>= 1) acc += __shfl_down(acc, o);
            if (lane == 0) gcur[r] = X[t * G4 + r] + acc;
        }
    }
}

// ================= redundant merge (device fn, 512 threads) =================
struct MrgSm {
    double lse[BEAM]; double scl[BEAM];
    u64 rc[BEAM * BEAM];
    double gbv[8]; unsigned gbf[8]; unsigned winf;
    int pk[BEAM]; int ny[BEAM]; double val[BEAM];
};

__device__ __forceinline__ void do_merge(MrgSm* M, const double* __restrict__ part,
                                         const u64* __restrict__ cand,
                                         const double* __restrict__ sc_in,
                                         int m, int tid) {
    int wv = tid >> 6, lane = tid & 63;
    if (tid < BEAM) M->scl[tid] = sc_in[tid];
    // per-row lse (fp64)
    for (int r = wv; r < BEAM; r += 8) {
        double s = 0.0;
        for (int i = lane; i < NSTRIP; i += 64) s += part[r * NSTRIP + i];
        for (int o = 32; o; o >>= 1) s += __shfl_down(s, o);
        if (lane == 0) M->lse[r] = log(s);
    }
    // per-row top-10 over 1960 strip candidates (wave tournament, u64 keys)
    for (int r = wv; r < BEAM; r += 8) {
        u64 kk[31];
        int n = 0;
        for (int i = lane; i < CPR; i += 64) kk[n++] = cand[(size_t)r * CPR + i];
        for (; n < 31; ++n) kk[n] = 0ull;
        for (int round = 0; round < BEAM; ++round) {
            u64 mx = 0ull;
#pragma unroll
            for (int e = 0; e < 31; e++) if (kk[e] > mx) mx = kk[e];
            for (int o = 32; o; o >>= 1) { u64 t2 = __shfl_down(mx, o); if (t2 > mx) mx = t2; }
            u64 win = __shfl(mx, 0);
#pragma unroll
            for (int e = 0; e < 31; e++) if (kk[e] == win) kk[e] = 0ull;
            if (lane == 0) M->rc[r * BEAM + round] = win;
        }
    }
    __syncthreads();
    // global merge over 100 candidates (fp64 value, flat-index tiebreak)
    double cv = -1.0e308; unsigned cf = 0xFFFFFFFFu;
    if (tid < BEAM * BEAM) {
        u64 k0 = M->rc[tid];
        if (k0) {
            int r2 = tid / BEAM;
            float v = unfkey((unsigned)(k0 >> 32));
            unsigned p = ~((unsigned)k0);
            double v2;
            if (m == 0) v2 = (r2 == 0) ? ((double)v - M->lse[0]) : NEGD;
            else        v2 = ((double)v - M->lse[r2]) + M->scl[r2];
            cv = v2; cf = (unsigned)r2 * PV + p;
        }
    }
    for (int round = 0; round < BEAM; ++round) {
        double bv = cv; unsigned bf = cf;
        for (int o = 32; o; o >>= 1) {
            double ov = __shfl_down(bv, o);
            unsigned of = __shfl_down(bf, o);
            if (ov > bv || (ov == bv && of < bf)) { bv = ov; bf = of; }
        }
        if (lane == 0) { M->gbv[wv] = bv; M->gbf[wv] = bf; }
        __syncthreads();
        if (tid == 0) {
            double xv = M->gbv[0]; unsigned xf = M->gbf[0];
            for (int i = 1; i < 8; i++) {
                if (M->gbv[i] > xv || (M->gbv[i] == xv && M->gbf[i] < xf)) { xv = M->gbv[i]; xf = M->gbf[i]; }
            }
            M->winf = xf;
            int pk = (int)(xf / PV);
            int ny = (int)(xf - (unsigned)pk * PV);
            M->pk[round] = pk; M->ny[round] = ny; M->val[round] = xv;
        }
        __syncthreads();
        if (cf == M->winf) { cv = -1.0e308; cf = 0xFFFFFFFFu; }
        __syncthreads();
    }
}

// ================= fused merge(t-1) + gates (125 x 512) =================
__global__ __launch_bounds__(512) void k_gates_m(
        const float* __restrict__ decEmb, const float* __restrict__ Wih,
        const float* __restrict__ Whh, const float* __restrict__ bih,
        const float* __restrict__ bhh,
        const double* __restrict__ part, const u64* __restrict__ cand,
        const double* __restrict__ sc_in, double* __restrict__ sc_out,
        const float* __restrict__ h2w, const float* __restrict__ c2w,
        float* __restrict__ dc, const float* __restrict__ dh0,
        int* __restrict__ prevK, int* __restrict__ nextY,
        float* __restrict__ gates, int t) {
    __shared__ float e_lds[BEAM * ED];
    __shared__ float h_lds[BEAM * HD];
    __shared__ MrgSm M;
    int tid = threadIdx.x, bid = blockIdx.x;
    int wv = tid >> 6, lane = tid & 63;

    if (t > 0) {
        int m = t - 1;
        do_merge(&M, part, cand, sc_in, m, tid);
        if (tid < BEAM && bid == 0) {
            sc_out[tid] = M.val[tid];
            prevK[m * BEAM + tid] = M.pk[tid];
            nextY[m * BEAM + tid] = M.ny[tid];
        }
        __syncthreads();
        for (int idx = tid; idx < BEAM * HD; idx += 512) {
            int b = idx / HD, j = idx - b * HD;
            h_lds[idx] = h2w[M.pk[b] * HD + j];
            e_lds[idx] = decEmb[(size_t)M.ny[b] * ED + j];
            if (bid == 0) dc[idx] = c2w[M.pk[b] * HD + j];
        }
    } else {
        for (int idx = tid; idx < BEAM * HD; idx += 512) {
            int b = idx / HD, j = idx - b * HD;
            int tk = (b == 0) ? 2 : 1;
            h_lds[idx] = dh0[idx];
            e_lds[idx] = decEmb[(size_t)tk * ED + j];
        }
    }
    __syncthreads();

    // gates: 16 rows/block, 2 rows/wave (per-row math identical to R4 k_gates)
    for (int rr = 0; rr < 2; ++rr) {
        int r = bid * 16 + wv * 2 + rr;
        const float* wi = Wih + (size_t)r * ED;
        const float* wh = Whh + (size_t)r * HD;
        float acc[BEAM];
#pragma unroll
        for (int b = 0; b < BEAM; b++) acc[b] = 0.f;
        for (int ki = 0; ki < 8; ki++) {
            int k = ki * 64 + lane;
            if (k < ED) {
                float w = wi[k];
#pragma unroll
                for (int b = 0; b < BEAM; b++) acc[b] += w * e_lds[b * ED + k];
            }
        }
        for (int ki = 0; ki < 8; ki++) {
            int k = ki * 64 + lane;
            if (k < HD) {
                float w = wh[k];
#pragma unroll
                for (int b = 0; b < BEAM; b++) acc[b] += w * h_lds[b * HD + k];
            }
        }
#pragma unroll
        for (int b = 0; b < BEAM; b++) {
            float v = acc[b];
            for (int o = 32; o; o >>= 1) v += __shfl_down(v, o);
            acc[b] = v;
        }
        if (lane == 0) {
            float bb = bih[r] + bhh[r];
#pragma unroll
            for (int b = 0; b < BEAM; b++) gates[b * G4 + r] = acc[b] + bb;
        }
    }
}

// ---------------- attn + oproj (125 x 256, R4-validated) ----------------
__global__ __launch_bounds__(256) void k_attn_oproj(
        const float* __restrict__ gates, const float* __restrict__ c_ws,
        const float* __restrict__ context, const float* __restrict__ attnW,
        float* __restrict__ h2_ws, float* __restrict__ c2_ws, float* __restrict__ o_ws) {
    __shared__ float h2_lds[BEAM * HD];
    __shared__ float wctx_lds[BEAM * HD];
    __shared__ float s_lds[BEAM * SLEN];
    __shared__ float a_lds[BEAM * SLEN];
    int tid = threadIdx.x;
    int wv = tid >> 6, lane = tid & 63;
    for (int idx = tid; idx < BEAM * HD; idx += 256) {
        int b = idx / HD, j = idx - b * HD;
        float gi = gates[b * G4 + j], gf = gates[b * G4 + HD + j];
        float gg = gates[b * G4 + 2 * HD + j], go = gates[b * G4 + 3 * HD + j];
        float c = sigf(gf) * c_ws[idx] + sigf(gi) * tanhf(gg);
        float h2 = sigf(go) * tanhf(c);
        h2_lds[idx] = h2;
        if (blockIdx.x == 0) { c2_ws[idx] = c; h2_ws[idx] = h2; }
    }
    __syncthreads();
    for (int si = 0; si < 8; ++si) {
        int s = wv + 4 * si;
        float acc[BEAM];
#pragma unroll
        for (int b = 0; b < BEAM; b++) acc[b] = 0.f;
        for (int ki = 0; ki < 8; ki++) {
            int k = ki * 64 + lane;
            if (k < HD) {
                float c = context[s * HD + k];
#pragma unroll
                for (int b = 0; b < BEAM; b++) acc[b] += c * h2_lds[b * HD + k];
            }
        }
#pragma unroll
        for (int b = 0; b < BEAM; b++) {
            float v = acc[b];
            for (int o = 32; o; o >>= 1) v += __shfl_down(v, o);
            if (lane == 0) s_lds[b * SLEN + s] = v;
        }
    }
    __syncthreads();
    if (wv == 0) {
        for (int b = 0; b < BEAM; ++b) {
            float v = (lane < SLEN) ? s_lds[b * SLEN + lane] : -INFINITY;
            float m = v;
            for (int o = 32; o; o >>= 1) m = fmaxf(m, __shfl_xor(m, o));
            float e = (lane < SLEN) ? expf(v - m) : 0.f;
            float sum = e;
            for (int o = 32; o; o >>= 1) sum += __shfl_xor(sum, o);
            if (lane < SLEN) a_lds[b * SLEN + lane] = e / sum;
        }
    }
    __syncthreads();
    {
        float w0[BEAM], w1[BEAM];
#pragma unroll
        for (int b = 0; b < BEAM; b++) { w0[b] = 0.f; w1[b] = 0.f; }
        int j0 = tid, j1 = tid + 256;
        for (int s = 0; s < SLEN; ++s) {
            float c0 = (j0 < HD) ? context[s * HD + j0] : 0.f;
            float c1 = (j1 < HD) ? context[s * HD + j1] : 0.f;
#pragma unroll
            for (int b = 0; b < BEAM; b++) {
                float a = a_lds[b * SLEN + s];
                w0[b] += a * c0; w1[b] += a * c1;
            }
        }
#pragma unroll
        for (int b = 0; b < BEAM; b++) {
            if (j0 < HD) wctx_lds[b * HD + j0] = w0[b];
            if (j1 < HD) wctx_lds[b * HD + j1] = w1[b];
        }
    }
    __syncthreads();
    int j = blockIdx.x * 4 + wv;
    const float* w = attnW + (size_t)j * 1000;
    float acc[BEAM];
#pragma unroll
    for (int b = 0; b < BEAM; b++) acc[b] = 0.f;
    for (int ki = 0; ki < 16; ki++) {
        int k = ki * 64 + lane;
        if (k < 1000) {
            float wk = w[k];
#pragma unroll
            for (int b = 0; b < BEAM; b++) {
                float h = (k < HD) ? h2_lds[b * HD + k] : wctx_lds[b * HD + k - HD];
                acc[b] += wk * h;
            }
        }
    }
#pragma unroll
    for (int b = 0; b < BEAM; b++) {
        float v = acc[b];
        for (int o = 32; o; o >>= 1) v += __shfl_down(v, o);
        acc[b] = v;
    }
    if (lane == 0) {
#pragma unroll
        for (int b = 0; b < BEAM; b++) o_ws[b * HD + j] = tanhf(acc[b]);
    }
}

// ---------------- fused logits + strip top-10 + fp64 sumexp ----------------
// 196 blocks x 1024 threads: 4-way K-split per column (R4 k_logits4 association),
// ~200K threads (~3 waves/SIMD) — fixes R10's <1 wave/SIMD latency-bound regime.
__global__ __launch_bounds__(1024) void k_logits_topk(
        const float* __restrict__ outW4, const float* __restrict__ outB,
        const float* __restrict__ o_ws, u64* __restrict__ cand,
        double* __restrict__ part) {
    __shared__ __align__(16) char sm[61440];
    float4* o4 = (float4*)sm;                 // [0, 20480): 1250 float4 = 20000 B
    float*  pt = (float*)(sm + 20480);        // [20480, 61440): part [4][256][10] = 40960 B
    int tid = threadIdx.x, bid = blockIdx.x;
    int lane = tid & 63;
    int col = tid & 255, kc = tid >> 8;
    for (int idx = tid; idx < BEAM * 125; idx += 1024) {
        int b = idx / 125, kb = idx - b * 125;
        o4[idx] = *(const float4*)(o_ws + b * HD + kb * 4);
    }
    __syncthreads();
    int p = bid * 256 + col;
    bool valid = (p < PV);
    int pc = valid ? p : (PV - 1);
    {
        float acc[BEAM];
#pragma unroll
        for (int b = 0; b < BEAM; b++) acc[b] = 0.f;
        int kb0 = kc * 32, kb1 = (kc == 3) ? 125 : (kb0 + 32);
        const float4* wp = (const float4*)outW4;
        for (int kb = kb0; kb < kb1; ++kb) {
            float4 w = wp[(size_t)kb * PV + pc];
#pragma unroll
            for (int b = 0; b < BEAM; b++) {
                float4 o = o4[b * 125 + kb];
                acc[b] += w.x * o.x + w.y * o.y + w.z * o.z + w.w * o.w;
            }
        }
#pragma unroll
        for (int b = 0; b < BEAM; b++) pt[(kc * 256 + col) * BEAM + b] = acc[b];
    }
    __syncthreads();
    float lg[BEAM];
    if (tid < 256) {
        float ob = outB[pc];
#pragma unroll
        for (int b = 0; b < BEAM; b++)
            lg[b] = pt[(0 * 256 + tid) * BEAM + b] + pt[(1 * 256 + tid) * BEAM + b]
                  + pt[(2 * 256 + tid) * BEAM + b] + pt[(3 * 256 + tid) * BEAM + b] + ob;
    }
    __syncthreads();   // all pt reads done; o4 long dead
    double* pd = (double*)sm;            // reuse o4 region: 256*10*8 = 20480 B
    u64*    kl = (u64*)(sm + 20480);     // reuse pt region: 10*256*8 = 20480 B
    if (tid < 256) {
#pragma unroll
        for (int b = 0; b < BEAM; b++) {
            pd[b * 256 + tid] = valid ? exp((double)lg[b]) : 0.0;
            kl[b * 256 + tid] = valid ? (((u64)fkey(lg[b]) << 32) | (unsigned)(~(unsigned)p)) : 0ull;
        }
    }
    __syncthreads();
    int wv = tid >> 6;
    if (wv < BEAM) {
        int r = wv;
        // fp64 partial sumexp (same 4-term + shuffle order as R10)
        double s = pd[r * 256 + lane] + pd[r * 256 + 64 + lane]
                 + pd[r * 256 + 128 + lane] + pd[r * 256 + 192 + lane];
        for (int o = 32; o; o >>= 1) s += __shfl_down(s, o);
        if (lane == 0) part[r * NSTRIP + bid] = s;
        // per-strip per-row top-10 (u64 keys, exact tournament)
        u64 kk[4];
#pragma unroll
        for (int j = 0; j < 4; j++) kk[j] = kl[r * 256 + j * 64 + lane];
        for (int round = 0; round < BEAM; round++) {
            u64 m = kk[0];
            if (kk[1] > m) m = kk[1];
            if (kk[2] > m) m = kk[2];
            if (kk[3] > m) m = kk[3];
            for (int o = 32; o; o >>= 1) {
                u64 t2 = __shfl_down(m, o);
                if (t2 > m) m = t2;
            }
            u64 win = __shfl(m, 0);
#pragma unroll
            for (int j = 0; j < 4; j++) if (kk[j] == win) kk[j] = 0ull;
            if (lane == 0) cand[(size_t)r * CPR + bid * 10 + round] = win;
        }
    }
}

// ---------------- final merge(31) + traceback (1 x 512) ----------------
__global__ __launch_bounds__(512) void k_final(
        const double* __restrict__ part, const u64* __restrict__ cand,
        const double* __restrict__ sc_in,
        int* __restrict__ prevK, int* __restrict__ nextY, int* __restrict__ out) {
    __shared__ MrgSm M;
    int tid = threadIdx.x;
    do_merge(&M, part, cand, sc_in, MAXLEN - 1, tid);
    if (tid < BEAM) {
        prevK[(MAXLEN - 1) * BEAM + tid] = M.pk[tid];
        nextY[(MAXLEN - 1) * BEAM + tid] = M.ny[tid];
    }
    __syncthreads();
    if (tid < BEAM) {
        int cur = tid;
        for (int tt = MAXLEN - 1; tt >= 0; tt--) {
            out[tid * MAXLEN + tt] = nextY[tt * BEAM + cur];
            cur = prevK[tt * BEAM + cur];
        }
    }
}

// ======================================================================
// R4 fallback kernels (used only when ws is too small for transposed W)
// ======================================================================
__global__ __launch_bounds__(1024) void k_gates(
        const float* __restrict__ dec_emb, const float* __restrict__ Wih,
        const float* __restrict__ Whh, const float* __restrict__ bih,
        const float* __restrict__ bhh, const int* __restrict__ tokens,
        const float* __restrict__ h_ws, float* __restrict__ gates) {
    __shared__ float e_lds[BEAM * ED];
    __shared__ float h_lds[BEAM * HD];
    int tid = threadIdx.x;
    for (int idx = tid; idx < BEAM * ED; idx += 1024) {
        int b = idx / ED, k = idx - b * ED;
        e_lds[idx] = dec_emb[(size_t)tokens[b] * ED + k];
        h_lds[idx] = h_ws[idx];
    }
    __syncthreads();
    int wv = tid >> 6, lane = tid & 63;
    int r = blockIdx.x * 16 + wv;
    const float* wi = Wih + (size_t)r * ED;
    const float* wh = Whh + (size_t)r * HD;
    float acc[BEAM];
#pragma unroll
    for (int b = 0; b < BEAM; b++) acc[b] = 0.f;
    for (int ki = 0; ki < 8; ki++) {
        int k = ki * 64 + lane;
        if (k < ED) {
            float w = wi[k];
#pragma unroll
            for (int b = 0; b < BEAM; b++) acc[b] += w * e_lds[b * ED + k];
        }
    }
    for (int ki = 0; ki < 8; ki++) {
        int k = ki * 64 + lane;
        if (k < HD) {
            float w = wh[k];
#pragma unroll
            for (int b = 0; b < BEAM; b++) acc[b] += w * h_lds[b * HD + k];
        }
    }
#pragma unroll
    for (int b = 0; b < BEAM; b++) {
        float v = acc[b];
        for (int o = 32; o; o >>= 1) v += __shfl_down(v, o);
        acc[b] = v;
    }
    if (lane == 0) {
        float bb = bih[r] + bhh[r];
#pragma unroll
        for (int b = 0; b < BEAM; b++) gates[b * G4 + r] = acc[b] + bb;
    }
}

__global__ void k_logits_f(const float* __restrict__ outW, const float* __restrict__ outB,
                           const float* __restrict__ o_ws, float* __restrict__ logits,
                           double* __restrict__ partials) {
    __shared__ float o_lds[BEAM * HD];
    __shared__ double ered[4][BEAM];
    int tid = threadIdx.x;
    for (int idx = tid; idx < BEAM * HD; idx += 256) o_lds[idx] = o_ws[idx];
    __syncthreads();
    int wv = tid >> 6, lane = tid & 63;
    int w = blockIdx.x * 4 + wv;
    double esum = 0.0;
    for (int pi = 0; pi < 16; pi++) {
        int p = w * 16 + pi;
        if (p >= PV) break;
        const float* wr = outW + (size_t)p * HD;
        float acc[BEAM];
#pragma unroll
        for (int b = 0; b < BEAM; b++) acc[b] = 0.f;
        for (int ki = 0; ki < 8; ki++) {
            int k = ki * 64 + lane;
            if (k < HD) {
                float x = wr[k];
#pragma unroll
                for (int b = 0; b < BEAM; b++) acc[b] += x * o_lds[b * HD + k];
            }
        }
#pragma unroll
        for (int b = 0; b < BEAM; b++)
            for (int o = 32; o; o >>= 1) acc[b] += __shfl_xor(acc[b], o);
        if (lane < BEAM) {
            float lg = 0.f;
#pragma unroll
            for (int b = 0; b < BEAM; b++) if (lane == b) lg = acc[b];
            lg += outB[p];
            logits[(size_t)lane * PV + p] = lg;
            esum += exp((double)lg);
        }
    }
    if (lane < BEAM) ered[wv][lane] = esum;
    __syncthreads();
    if (tid < BEAM) partials[blockIdx.x * BEAM + tid] =
        ered[0][tid] + ered[1][tid] + ered[2][tid] + ered[3][tid];
}

__global__ __launch_bounds__(256) void k_topk_row(const float* __restrict__ logits,
                                                  u64* __restrict__ cands) {
    const int CH = 1563;
    int r = blockIdx.x >> 5, ci = blockIdx.x & 31;
    int base = ci * CH;
    int tid = threadIdx.x;
    int wv = tid >> 6, lane = tid & 63;
    u64 key[7];
#pragma unroll
    for (int e = 0; e < 7; e++) {
        int p = base + e * 256 + tid;
        key[e] = 0ull;
        if (p < base + CH && p < PV) {
            float v = logits[(size_t)r * PV + p];
            key[e] = ((u64)fkey(v) << 32) | (unsigned)(~(unsigned)p);
        }
    }
    __shared__ u64 wred[4];
    __shared__ u64 winlds;
    for (int round = 0; round < BEAM; round++) {
        u64 mx = 0ull;
#pragma unroll
        for (int e = 0; e < 7; e++) if (key[e] > mx) mx = key[e];
        for (int o = 32; o; o >>= 1) {
            u64 other = __shfl_down(mx, o);
            if (other > mx) mx = other;
        }
        if (lane == 0) wred[wv] = mx;
        __syncthreads();
        if (tid == 0) {
            u64 wn = wred[0];
            for (int i = 1; i < 4; i++) if (wred[i] > wn) wn = wred[i];
            winlds = wn;
            cands[blockIdx.x * BEAM + round] = wn;
        }
        __syncthreads();
        u64 win = winlds;
#pragma unroll
        for (int e = 0; e < 7; e++) if (key[e] == win) key[e] = 0ull;
    }
}

__global__ __launch_bounds__(256) void k_merge(
        const double* __restrict__ partials, int npart,
        const u64* __restrict__ cands,
        double* __restrict__ scores, int* __restrict__ tokens,
        const float* __restrict__ h2_ws, const float* __restrict__ c2_ws,
        float* __restrict__ h_ws, float* __restrict__ c_ws,
        int* __restrict__ prevKs, int* __restrict__ nextYs, int t) {
    __shared__ double wredd[4];
    __shared__ double lse_lds[BEAM];
    __shared__ double sc_lds[BEAM];
    __shared__ double bwv[4];
    __shared__ unsigned bwf[4];
    __shared__ unsigned winf_s;
    __shared__ int pk_lds[BEAM];
    __shared__ int ny_lds[BEAM];
    __shared__ double val_lds[BEAM];
    int tid = threadIdx.x;
    int wv = tid >> 6, lane = tid & 63;
    if (tid < BEAM) sc_lds[tid] = scores[tid];
    for (int b = 0; b < BEAM; b++) {
        double s = 0.0;
        for (int j = tid; j < npart; j += 256) s += partials[j * BEAM + b];
        for (int o = 32; o; o >>= 1) s += __shfl_down(s, o);
        if (lane == 0) wredd[wv] = s;
        __syncthreads();
        if (tid == 0) lse_lds[b] = log(wredd[0] + wredd[1] + wredd[2] + wredd[3]);
        __syncthreads();
    }
    double   cv[13];
    unsigned cf[13];
#pragma unroll
    for (int e = 0; e < 13; e++) {
        int c = e * 256 + tid;
        cv[e] = -1.0e308; cf[e] = 0xFFFFFFFFu;
        if (c < 3200) {
            u64 k0 = cands[c];
            if (k0) {
                int r = c / 320;
                float v = unfkey((unsigned)(k0 >> 32));
                unsigned p = ~((unsigned)k0);
                double v2;
                if (t == 0) v2 = (r == 0) ? ((double)v - lse_lds[0]) : (double)NEGF;
                else        v2 = ((double)v - lse_lds[r]) + sc_lds[r];
                cv[e] = v2;
                cf[e] = (unsigned)r * PV + p;
            }
        }
    }
    for (int round = 0; round < BEAM; round++) {
        double bv = -1.0e308; unsigned bf = 0xFFFFFFFFu;
#pragma unroll
        for (int e = 0; e < 13; e++) {
            if (cv[e] > bv || (cv[e] == bv && cf[e] < bf)) { bv = cv[e]; bf = cf[e]; }
        }
        for (int o = 32; o; o >>= 1) {
            double ov = __shfl_down(bv, o);
            unsigned of = __shfl_down(bf, o);
            if (ov > bv || (ov == bv && of < bf)) { bv = ov; bf = of; }
        }
        if (lane == 0) { bwv[wv] = bv; bwf[wv] = bf; }
        __syncthreads();
        if (tid == 0) {
            double xv = bwv[0]; unsigned xf = bwf[0];
            for (int i = 1; i < 4; i++) {
                if (bwv[i] > xv || (bwv[i] == xv && bwf[i] < xf)) { xv = bwv[i]; xf = bwf[i]; }
            }
            winf_s = xf;
            int pk = (int)(xf / PV);
            int ny = (int)(xf - (unsigned)pk * PV);
            pk_lds[round] = pk; ny_lds[round] = ny; val_lds[round] = xv;
        }
        __syncthreads();
        unsigned wff = winf_s;
#pragma unroll
        for (int e = 0; e < 13; e++) {
            if (cf[e] == wff) { cv[e] = -1.0e308; cf[e] = 0xFFFFFFFFu; }
        }
    }
    if (tid < BEAM) {
        scores[tid] = val_lds[tid];
        tokens[tid] = ny_lds[tid];
        prevKs[t * BEAM + tid] = pk_lds[tid];
        nextYs[t * BEAM + tid] = ny_lds[tid];
    }
    __syncthreads();
    for (int idx = tid; idx < BEAM * HD; idx += 256) {
        int i = idx / HD, j = idx - i * HD;
        h_ws[idx] = h2_ws[pk_lds[i] * HD + j];
        c_ws[idx] = c2_ws[pk_lds[i] * HD + j];
    }
}

__global__ void k_traceback(const int* __restrict__ prevKs, const int* __restrict__ nextYs,
                            int* __restrict__ out) {
    int k = threadIdx.x;
    if (k >= BEAM) return;
    int cur = k;
    for (int t = MAXLEN - 1; t >= 0; t--) {
        out[k * MAXLEN + t] = nextYs[t * BEAM + cur];
        cur = prevKs[t * BEAM + cur];
    }
}

extern "C" void kernel_launch(void* const* d_in, const int* in_sizes, int n_in,
                              void* d_out, int out_size, void* d_ws, size_t ws_size,
                              hipStream_t stream) {
    const int*   g_seq  = (const int*)  d_in[0];
    const float* encEmb = (const float*)d_in[1];
    const float* encWih = (const float*)d_in[2];
    const float* encWhh = (const float*)d_in[3];
    const float* encBih = (const float*)d_in[4];
    const float* encBhh = (const float*)d_in[5];
    const float* decEmb = (const float*)d_in[6];
    const float* decWih = (const float*)d_in[7];
    const float* decWhh = (const float*)d_in[8];
    const float* decBih = (const float*)d_in[9];
    const float* decBhh = (const float*)d_in[10];
    const float* attnW  = (const float*)d_in[11];
    const float* outW   = (const float*)d_in[12];
    const float* outB   = (const float*)d_in[13];

    float* ws = (float*)d_ws;
    float*  X     = ws + OFF_X;
    float*  cbuf  = ws + OFF_CBUF;
    float*  gbuf  = ws + OFF_GBUF;
    float*  ctx   = ws + OFF_CTX;
    float*  dh    = ws + OFF_DH;
    float*  dc    = ws + OFF_DC;
    float*  dg    = ws + OFF_DG;
    float*  h2    = ws + OFF_H2;
    float*  c2    = ws + OFF_C2;
    float*  o     = ws + OFF_O;
    double* scb   = (double*)(ws + OFF_SCD);   // ping-pong pair of 10 doubles
    int*    tok   = (int*)(ws + OFF_TOK);
    int*    prevK = (int*)(ws + OFF_PREVK);
    int*    nextY = (int*)(ws + OFF_NEXTY);
    float*  outW4 = ws + OFF_OWT;

    bool bigws = (ws_size >= NEED_T_BYTES);

    k_prep<<<16000, 256, 0, stream>>>(g_seq, encEmb, encWih, encBih, encBhh, X, cbuf);
    if (bigws) k_transpose4<<<dim3(782, 8), 256, 0, stream>>>(outW, outW4);

    for (int t = 0; t <= SLEN; t++)
        k_enc<<<250, 256, 0, stream>>>(encWhh, X, gbuf, cbuf, ctx, dh, dc, scb, tok, t);

    if (bigws) {
        double* part = (double*)(ws + OFF_PARTD);
        u64*    cand = (u64*)(ws + OFF_CAND);
        for (int t = 0; t < MAXLEN; t++) {
            int m = t - 1;
            const double* sin = scb + ((m & 1) ? 10 : 0);
            double*       sout = scb + (((m + 1) & 1) ? 10 : 0);
            if (t == 0) { sin = scb; sout = scb + 10; }   // unused at t==0
            k_gates_m<<<125, 512, 0, stream>>>(decEmb, decWih, decWhh, decBih, decBhh,
                                               part, cand, sin, sout,
                                               h2, c2, dc, dh, prevK, nextY, dg, t);
            k_attn_oproj<<<125, 256, 0, stream>>>(dg, dc, ctx, attnW, h2, c2, o);
            k_logits_topk<<<NSTRIP, 1024, 0, stream>>>(outW4, outB, o, cand, part);
        }
        int mf = MAXLEN - 1;
        k_final<<<1, 512, 0, stream>>>(part, cand, scb + ((mf & 1) ? 10 : 0),
                                       prevK, nextY, (int*)d_out);
    } else {
        // R4-validated fallback (row-major out_W)
        double* part  = (double*)(ws + OFF_PARTF);
        u64*    cand  = (u64*)(ws + OFF_CANDF);
        float*  logits = ws + OFF_LOG;
        const int npart = 782;
        for (int t = 0; t < MAXLEN; t++) {
            k_gates<<<125, 1024, 0, stream>>>(decEmb, decWih, decWhh, decBih, decBhh, tok, dh, dg);
            k_attn_oproj<<<125, 256, 0, stream>>>(dg, dc, ctx, attnW, h2, c2, o);
            k_logits_f<<<782, 256, 0, stream>>>(outW, outB, o, logits, part);
            k_topk_row<<<320, 256, 0, stream>>>(logits, cand);
            k_merge<<<1, 256, 0, stream>>>(part, npart, cand, scb, tok, h2, c2, dh, dc, prevK, nextY, t);
        }
        k_traceback<<<1, 64, 0, stream>>>(prevK, nextY, (int*)d_out);
    }
}

// Round 12
// 4009.751 us; speedup vs baseline: 3.2269x; 1.1547x over previous
//
#include <hip/hip_runtime.h>
#include <math.h>

#define BEAM   10
#define MAXLEN 32
#define SLEN   32
#define HD     500
#define ED     500
#define G4     2000
#define PV     50000
#define NEGF   (-1e30f)
#define NEGD   (-1.0e30)

#define NSTRIP 196               // logits strip blocks (196*256 >= 50000)
#define CPR    (NSTRIP * BEAM)   // 1960 candidates per row

typedef unsigned long long u64;

// ---------------- ws layout (float element offsets) ----------------
#define OFF_X      0
#define OFF_CBUF   64000
#define OFF_GBUF   65000
#define OFF_CTX    69000
#define OFF_DH     85000
#define OFF_DC     90000
#define OFF_DG     95000
#define OFF_H2     115000
#define OFF_C2     120000
#define OFF_O      125000
#define OFF_SCD    135000   // double[20] score ping-pong (40 float slots)
#define OFF_TOK    135040   // 10 ints (fallback path)
#define OFF_PREVK  135060   // 320 ints
#define OFF_NEXTY  135380   // 320 ints
// fallback-path regions (R4 layout)
#define OFF_PARTF  136000   // double[7820]
#define OFF_CANDF  152000   // u64[3200]
#define OFF_LOG    160000   // fallback logits buffer
// new-path regions (inside fallback LOG region; paths exclusive)
#define OFF_PARTD  160284   // double[1960]
#define OFF_CAND   165604   // u64[19600]
#define OFF_OWT    660000   // float4-blocked transposed out_W (100 MB)
#define NEED_T_BYTES ((size_t)(OFF_OWT + (size_t)HD * PV) * 4)

__device__ __forceinline__ float sigf(float x) { return 1.f / (1.f + expf(-x)); }

__device__ __forceinline__ unsigned fkey(float f) {
    unsigned u = __float_as_uint(f);
    return (u & 0x80000000u) ? ~u : (u | 0x80000000u);
}
__device__ __forceinline__ float unfkey(unsigned k) {
    unsigned u = (k & 0x80000000u) ? (k & 0x7fffffffu) : ~k;
    return __uint_as_float(u);
}

// ---------------- prep ----------------
__global__ void k_prep(const int* __restrict__ g_seq, const float* __restrict__ enc_emb,
                       const float* __restrict__ Wih, const float* __restrict__ bih,
                       const float* __restrict__ bhh, float* __restrict__ X,
                       float* __restrict__ cbuf0) {
    if (blockIdx.x == 0) {
        for (int j = threadIdx.x; j < HD; j += 256) cbuf0[j] = 0.f;
    }
    int wv = (blockIdx.x * blockDim.x + threadIdx.x) >> 6;
    int lane = threadIdx.x & 63;
    if (wv >= SLEN * G4) return;
    int t = wv / G4, r = wv - t * G4;
    const float* emb = enc_emb + (size_t)g_seq[t] * ED;
    const float* w = Wih + (size_t)r * ED;
    float acc = 0.f;
    for (int ki = 0; ki < 8; ki++) { int k = ki * 64 + lane; if (k < ED) acc += emb[k] * w[k]; }
    for (int o = 32; o; o >>= 1) acc += __shfl_down(acc, o);
    if (lane == 0) X[t * G4 + r] = acc + bih[r] + bhh[r];
}

// ---------------- out_W blocked transpose ----------------
__global__ void k_transpose4(const float* __restrict__ outW, float* __restrict__ outW4) {
    __shared__ float t_lds[64][65];
    int tid = threadIdx.x;
    int pbase = blockIdx.x * 64, kbase = blockIdx.y * 64;
    for (int e = 0; e < 16; e++) {
        int idx = e * 256 + tid; int pl = idx >> 6, kl = idx & 63;
        int pp = pbase + pl, kk = kbase + kl;
        t_lds[pl][kl] = (pp < PV && kk < HD) ? outW[(size_t)pp * HD + kk] : 0.f;
    }
    __syncthreads();
    for (int e = 0; e < 4; e++) {
        int idx = e * 256 + tid;
        int pl = idx & 63, kb = idx >> 6;
        int pp = pbase + pl;
        int kglob = kbase + kb * 4;
        if (pp < PV && kglob < HD) {
            float4 v;
            v.x = t_lds[pl][kb * 4 + 0];
            v.y = t_lds[pl][kb * 4 + 1];
            v.z = t_lds[pl][kb * 4 + 2];
            v.w = t_lds[pl][kb * 4 + 3];
            *(float4*)(outW4 + ((size_t)(kbase / 4 + kb) * PV + pp) * 4) = v;
        }
    }
}

// ---------------- encoder step (R4-validated) ----------------
__global__ void k_enc(const float* __restrict__ Whh, const float* __restrict__ X,
                      float* __restrict__ gbuf, float* __restrict__ cbuf,
                      float* __restrict__ context, float* __restrict__ dec_h,
                      float* __restrict__ dec_c, double* __restrict__ scores,
                      int* __restrict__ tokens, int t) {
    __shared__ float h_lds[HD];
    const float* gprev = gbuf + ((t + 1) & 1) * G4;
    float*       gcur  = gbuf + (t & 1) * G4;
    const float* cprev = cbuf + ((t + 1) & 1) * HD;
    float*       ccur  = cbuf + (t & 1) * HD;
    int tid = threadIdx.x;
    if (t > 0) {
        for (int j = tid; j < HD; j += 256) {
            float gi = gprev[j], gf = gprev[HD + j], gg = gprev[2 * HD + j], go = gprev[3 * HD + j];
            float c = sigf(gf) * cprev[j] + sigf(gi) * tanhf(gg);
            float h = sigf(go) * tanhf(c);
            h_lds[j] = h;
            if (blockIdx.x == 0) {
                ccur[j] = c;
                context[(t - 1) * HD + j] = h;
                if (t == SLEN) {
                    for (int b = 0; b < BEAM; b++) { dec_h[b * HD + j] = h; dec_c[b * HD + j] = c; }
                }
            }
        }
    } else {
        for (int j = tid; j < HD; j += 256) h_lds[j] = 0.f;
    }
    if (t == SLEN && blockIdx.x == 0 && tid == 0) {
        for (int b = 0; b < BEAM; b++) scores[b] = 0.0;
        tokens[0] = 2; for (int b = 1; b < BEAM; b++) tokens[b] = 1;
    }
    __syncthreads();
    if (t < SLEN) {
        int wv = blockIdx.x * 4 + (tid >> 6), lane = tid & 63;
        for (int r = wv; r < G4; r += 1000) {
            const float* w = Whh + (size_t)r * HD;
            float acc = 0.f;
            for (int ki = 0; ki < 8; ki++) { int k = ki * 64 + lane; if (k < HD) acc += h_lds[k] * w[k]; }
            for (int o = 32; o; o >>= 1) acc += __shfl_down(acc, o);
            if (lane == 0) gcur[r] = X[t * G4 + r] + acc;
        }
    }
}

// ================= redundant merge (device fn, 512 threads) =================
struct MrgSm {
    double lse[BEAM]; double scl[BEAM];
    u64 rc[BEAM * BEAM];
    double gbv[8]; unsigned gbf[8]; unsigned winf;
    int pk[BEAM]; int ny[BEAM]; double val[BEAM];
};

__device__ __forceinline__ void do_merge(MrgSm* M, const double* __restrict__ part,
                                         const u64* __restrict__ cand,
                                         const double* __restrict__ sc_in,
                                         int m, int tid) {
    int wv = tid >> 6, lane = tid & 63;
    if (tid < BEAM) M->scl[tid] = sc_in[tid];
    // per-row lse (fp64)
    for (int r = wv; r < BEAM; r += 8) {
        double s = 0.0;
        for (int i = lane; i < NSTRIP; i += 64) s += part[r * NSTRIP + i];
        for (int o = 32; o; o >>= 1) s += __shfl_down(s, o);
        if (lane == 0) M->lse[r] = log(s);
    }
    // per-row top-10 over 1960 strip candidates (wave tournament, u64 keys).
    // STATIC indexing: kk[e] with compile-time e -> stays in VGPRs.
    // (R11 used kk[n++] with runtime n -> scratch spill -> ~5x slowdown, rule #20.)
    for (int r = wv; r < BEAM; r += 8) {
        u64 kk[31];
#pragma unroll
        for (int e = 0; e < 31; e++) {
            int i = lane + e * 64;
            kk[e] = (i < CPR) ? cand[(size_t)r * CPR + i] : 0ull;
        }
        for (int round = 0; round < BEAM; ++round) {
            u64 mx = 0ull;
#pragma unroll
            for (int e = 0; e < 31; e++) if (kk[e] > mx) mx = kk[e];
            for (int o = 32; o; o >>= 1) { u64 t2 = __shfl_down(mx, o); if (t2 > mx) mx = t2; }
            u64 win = __shfl(mx, 0);
#pragma unroll
            for (int e = 0; e < 31; e++) if (kk[e] == win) kk[e] = 0ull;
            if (lane == 0) M->rc[r * BEAM + round] = win;
        }
    }
    __syncthreads();
    // global merge over 100 candidates (fp64 value, flat-index tiebreak)
    double cv = -1.0e308; unsigned cf = 0xFFFFFFFFu;
    if (tid < BEAM * BEAM) {
        u64 k0 = M->rc[tid];
        if (k0) {
            int r2 = tid / BEAM;
            float v = unfkey((unsigned)(k0 >> 32));
            unsigned p = ~((unsigned)k0);
            double v2;
            if (m == 0) v2 = (r2 == 0) ? ((double)v - M->lse[0]) : NEGD;
            else        v2 = ((double)v - M->lse[r2]) + M->scl[r2];
            cv = v2; cf = (unsigned)r2 * PV + p;
        }
    }
    for (int round = 0; round < BEAM; ++round) {
        double bv = cv; unsigned bf = cf;
        for (int o = 32; o; o >>= 1) {
            double ov = __shfl_down(bv, o);
            unsigned of = __shfl_down(bf, o);
            if (ov > bv || (ov == bv && of < bf)) { bv = ov; bf = of; }
        }
        if (lane == 0) { M->gbv[wv] = bv; M->gbf[wv] = bf; }
        __syncthreads();
        if (tid == 0) {
            double xv = M->gbv[0]; unsigned xf = M->gbf[0];
            for (int i = 1; i < 8; i++) {
                if (M->gbv[i] > xv || (M->gbv[i] == xv && M->gbf[i] < xf)) { xv = M->gbv[i]; xf = M->gbf[i]; }
            }
            M->winf = xf;
            int pk = (int)(xf / PV);
            int ny = (int)(xf - (unsigned)pk * PV);
            M->pk[round] = pk; M->ny[round] = ny; M->val[round] = xv;
        }
        __syncthreads();
        if (cf == M->winf) { cv = -1.0e308; cf = 0xFFFFFFFFu; }
        __syncthreads();
    }
}

// ================= fused merge(t-1) + gates (125 x 512) =================
__global__ __launch_bounds__(512) void k_gates_m(
        const float* __restrict__ decEmb, const float* __restrict__ Wih,
        const float* __restrict__ Whh, const float* __restrict__ bih,
        const float* __restrict__ bhh,
        const double* __restrict__ part, const u64* __restrict__ cand,
        const double* __restrict__ sc_in, double* __restrict__ sc_out,
        const float* __restrict__ h2w, const float* __restrict__ c2w,
        float* __restrict__ dc, const float* __restrict__ dh0,
        int* __restrict__ prevK, int* __restrict__ nextY,
        float* __restrict__ gates, int t) {
    __shared__ float e_lds[BEAM * ED];
    __shared__ float h_lds[BEAM * HD];
    __shared__ MrgSm M;
    int tid = threadIdx.x, bid = blockIdx.x;
    int wv = tid >> 6, lane = tid & 63;

    if (t > 0) {
        int m = t - 1;
        do_merge(&M, part, cand, sc_in, m, tid);
        if (tid < BEAM && bid == 0) {
            sc_out[tid] = M.val[tid];
            prevK[m * BEAM + tid] = M.pk[tid];
            nextY[m * BEAM + tid] = M.ny[tid];
        }
        __syncthreads();
        for (int idx = tid; idx < BEAM * HD; idx += 512) {
            int b = idx / HD, j = idx - b * HD;
            h_lds[idx] = h2w[M.pk[b] * HD + j];
            e_lds[idx] = decEmb[(size_t)M.ny[b] * ED + j];
            if (bid == 0) dc[idx] = c2w[M.pk[b] * HD + j];
        }
    } else {
        for (int idx = tid; idx < BEAM * HD; idx += 512) {
            int b = idx / HD, j = idx - b * HD;
            int tk = (b == 0) ? 2 : 1;
            h_lds[idx] = dh0[idx];
            e_lds[idx] = decEmb[(size_t)tk * ED + j];
        }
    }
    __syncthreads();

    // gates: 16 rows/block, 2 rows/wave (per-row math identical to R4 k_gates)
    for (int rr = 0; rr < 2; ++rr) {
        int r = bid * 16 + wv * 2 + rr;
        const float* wi = Wih + (size_t)r * ED;
        const float* wh = Whh + (size_t)r * HD;
        float acc[BEAM];
#pragma unroll
        for (int b = 0; b < BEAM; b++) acc[b] = 0.f;
        for (int ki = 0; ki < 8; ki++) {
            int k = ki * 64 + lane;
            if (k < ED) {
                float w = wi[k];
#pragma unroll
                for (int b = 0; b < BEAM; b++) acc[b] += w * e_lds[b * ED + k];
            }
        }
        for (int ki = 0; ki < 8; ki++) {
            int k = ki * 64 + lane;
            if (k < HD) {
                float w = wh[k];
#pragma unroll
                for (int b = 0; b < BEAM; b++) acc[b] += w * h_lds[b * HD + k];
            }
        }
#pragma unroll
        for (int b = 0; b < BEAM; b++) {
            float v = acc[b];
            for (int o = 32; o; o >>= 1) v += __shfl_down(v, o);
            acc[b] = v;
        }
        if (lane == 0) {
            float bb = bih[r] + bhh[r];
#pragma unroll
            for (int b = 0; b < BEAM; b++) gates[b * G4 + r] = acc[b] + bb;
        }
    }
}

// ---------------- attn + oproj (125 x 256, R4-validated) ----------------
__global__ __launch_bounds__(256) void k_attn_oproj(
        const float* __restrict__ gates, const float* __restrict__ c_ws,
        const float* __restrict__ context, const float* __restrict__ attnW,
        float* __restrict__ h2_ws, float* __restrict__ c2_ws, float* __restrict__ o_ws) {
    __shared__ float h2_lds[BEAM * HD];
    __shared__ float wctx_lds[BEAM * HD];
    __shared__ float s_lds[BEAM * SLEN];
    __shared__ float a_lds[BEAM * SLEN];
    int tid = threadIdx.x;
    int wv = tid >> 6, lane = tid & 63;
    for (int idx = tid; idx < BEAM * HD; idx += 256) {
        int b = idx / HD, j = idx - b * HD;
        float gi = gates[b * G4 + j], gf = gates[b * G4 + HD + j];
        float gg = gates[b * G4 + 2 * HD + j], go = gates[b * G4 + 3 * HD + j];
        float c = sigf(gf) * c_ws[idx] + sigf(gi) * tanhf(gg);
        float h2 = sigf(go) * tanhf(c);
        h2_lds[idx] = h2;
        if (blockIdx.x == 0) { c2_ws[idx] = c; h2_ws[idx] = h2; }
    }
    __syncthreads();
    for (int si = 0; si < 8; ++si) {
        int s = wv + 4 * si;
        float acc[BEAM];
#pragma unroll
        for (int b = 0; b < BEAM; b++) acc[b] = 0.f;
        for (int ki = 0; ki < 8; ki++) {
            int k = ki * 64 + lane;
            if (k < HD) {
                float c = context[s * HD + k];
#pragma unroll
                for (int b = 0; b < BEAM; b++) acc[b] += c * h2_lds[b * HD + k];
            }
        }
#pragma unroll
        for (int b = 0; b < BEAM; b++) {
            float v = acc[b];
            for (int o = 32; o; o >>= 1) v += __shfl_down(v, o);
            if (lane == 0) s_lds[b * SLEN + s] = v;
        }
    }
    __syncthreads();
    if (wv == 0) {
        for (int b = 0; b < BEAM; ++b) {
            float v = (lane < SLEN) ? s_lds[b * SLEN + lane] : -INFINITY;
            float m = v;
            for (int o = 32; o; o >>= 1) m = fmaxf(m, __shfl_xor(m, o));
            float e = (lane < SLEN) ? expf(v - m) : 0.f;
            float sum = e;
            for (int o = 32; o; o >>= 1) sum += __shfl_xor(sum, o);
            if (lane < SLEN) a_lds[b * SLEN + lane] = e / sum;
        }
    }
    __syncthreads();
    {
        float w0[BEAM], w1[BEAM];
#pragma unroll
        for (int b = 0; b < BEAM; b++) { w0[b] = 0.f; w1[b] = 0.f; }
        int j0 = tid, j1 = tid + 256;
        for (int s = 0; s < SLEN; ++s) {
            float c0 = (j0 < HD) ? context[s * HD + j0] : 0.f;
            float c1 = (j1 < HD) ? context[s * HD + j1] : 0.f;
#pragma unroll
            for (int b = 0; b < BEAM; b++) {
                float a = a_lds[b * SLEN + s];
                w0[b] += a * c0; w1[b] += a * c1;
            }
        }
#pragma unroll
        for (int b = 0; b < BEAM; b++) {
            if (j0 < HD) wctx_lds[b * HD + j0] = w0[b];
            if (j1 < HD) wctx_lds[b * HD + j1] = w1[b];
        }
    }
    __syncthreads();
    int j = blockIdx.x * 4 + wv;
    const float* w = attnW + (size_t)j * 1000;
    float acc[BEAM];
#pragma unroll
    for (int b = 0; b < BEAM; b++) acc[b] = 0.f;
    for (int ki = 0; ki < 16; ki++) {
        int k = ki * 64 + lane;
        if (k < 1000) {
            float wk = w[k];
#pragma unroll
            for (int b = 0; b < BEAM; b++) {
                float h = (k < HD) ? h2_lds[b * HD + k] : wctx_lds[b * HD + k - HD];
                acc[b] += wk * h;
            }
        }
    }
#pragma unroll
    for (int b = 0; b < BEAM; b++) {
        float v = acc[b];
        for (int o = 32; o; o >>= 1) v += __shfl_down(v, o);
        acc[b] = v;
    }
    if (lane == 0) {
#pragma unroll
        for (int b = 0; b < BEAM; b++) o_ws[b * HD + j] = tanhf(acc[b]);
    }
}

// ---------------- fused logits + strip top-10 + fp64 sumexp ----------------
// 196 blocks x 1024 threads: 4-way K-split per column (R4 k_logits4 association)
__global__ __launch_bounds__(1024) void k_logits_topk(
        const float* __restrict__ outW4, const float* __restrict__ outB,
        const float* __restrict__ o_ws, u64* __restrict__ cand,
        double* __restrict__ part) {
    __shared__ __align__(16) char sm[61440];
    float4* o4 = (float4*)sm;                 // [0, 20480): 1250 float4 = 20000 B
    float*  pt = (float*)(sm + 20480);        // [20480, 61440): part [4][256][10] = 40960 B
    int tid = threadIdx.x, bid = blockIdx.x;
    int lane = tid & 63;
    int col = tid & 255, kc = tid >> 8;
    for (int idx = tid; idx < BEAM * 125; idx += 1024) {
        int b = idx / 125, kb = idx - b * 125;
        o4[idx] = *(const float4*)(o_ws + b * HD + kb * 4);
    }
    __syncthreads();
    int p = bid * 256 + col;
    bool valid = (p < PV);
    int pc = valid ? p : (PV - 1);
    {
        float acc[BEAM];
#pragma unroll
        for (int b = 0; b < BEAM; b++) acc[b] = 0.f;
        int kb0 = kc * 32, kb1 = (kc == 3) ? 125 : (kb0 + 32);
        const float4* wp = (const float4*)outW4;
        for (int kb = kb0; kb < kb1; ++kb) {
            float4 w = wp[(size_t)kb * PV + pc];
#pragma unroll
            for (int b = 0; b < BEAM; b++) {
                float4 o = o4[b * 125 + kb];
                acc[b] += w.x * o.x + w.y * o.y + w.z * o.z + w.w * o.w;
            }
        }
#pragma unroll
        for (int b = 0; b < BEAM; b++) pt[(kc * 256 + col) * BEAM + b] = acc[b];
    }
    __syncthreads();
    float lg[BEAM];
    if (tid < 256) {
        float ob = outB[pc];
#pragma unroll
        for (int b = 0; b < BEAM; b++)
            lg[b] = pt[(0 * 256 + tid) * BEAM + b] + pt[(1 * 256 + tid) * BEAM + b]
                  + pt[(2 * 256 + tid) * BEAM + b] + pt[(3 * 256 + tid) * BEAM + b] + ob;
    }
    __syncthreads();   // all pt reads done; o4 long dead
    double* pd = (double*)sm;            // reuse o4 region: 256*10*8 = 20480 B
    u64*    kl = (u64*)(sm + 20480);     // reuse pt region: 10*256*8 = 20480 B
    if (tid < 256) {
#pragma unroll
        for (int b = 0; b < BEAM; b++) {
            pd[b * 256 + tid] = valid ? exp((double)lg[b]) : 0.0;
            kl[b * 256 + tid] = valid ? (((u64)fkey(lg[b]) << 32) | (unsigned)(~(unsigned)p)) : 0ull;
        }
    }
    __syncthreads();
    int wv = tid >> 6;
    if (wv < BEAM) {
        int r = wv;
        double s = pd[r * 256 + lane] + pd[r * 256 + 64 + lane]
                 + pd[r * 256 + 128 + lane] + pd[r * 256 + 192 + lane];
        for (int o = 32; o; o >>= 1) s += __shfl_down(s, o);
        if (lane == 0) part[r * NSTRIP + bid] = s;
        u64 kk[4];
#pragma unroll
        for (int j = 0; j < 4; j++) kk[j] = kl[r * 256 + j * 64 + lane];
        for (int round = 0; round < BEAM; round++) {
            u64 m = kk[0];
            if (kk[1] > m) m = kk[1];
            if (kk[2] > m) m = kk[2];
            if (kk[3] > m) m = kk[3];
            for (int o = 32; o; o >>= 1) {
                u64 t2 = __shfl_down(m, o);
                if (t2 > m) m = t2;
            }
            u64 win = __shfl(m, 0);
#pragma unroll
            for (int j = 0; j < 4; j++) if (kk[j] == win) kk[j] = 0ull;
            if (lane == 0) cand[(size_t)r * CPR + bid * 10 + round] = win;
        }
    }
}

// ---------------- final merge(31) + traceback (1 x 512) ----------------
__global__ __launch_bounds__(512) void k_final(
        const double* __restrict__ part, const u64* __restrict__ cand,
        const double* __restrict__ sc_in,
        int* __restrict__ prevK, int* __restrict__ nextY, int* __restrict__ out) {
    __shared__ MrgSm M;
    int tid = threadIdx.x;
    do_merge(&M, part, cand, sc_in, MAXLEN - 1, tid);
    if (tid < BEAM) {
        prevK[(MAXLEN - 1) * BEAM + tid] = M.pk[tid];
        nextY[(MAXLEN - 1) * BEAM + tid] = M.ny[tid];
    }
    __syncthreads();
    if (tid < BEAM) {
        int cur = tid;
        for (int tt = MAXLEN - 1; tt >= 0; tt--) {
            out[tid * MAXLEN + tt] = nextY[tt * BEAM + cur];
            cur = prevK[tt * BEAM + cur];
        }
    }
}

// ======================================================================
// R4 fallback kernels (used only when ws is too small for transposed W)
// ======================================================================
__global__ __launch_bounds__(1024) void k_gates(
        const float* __restrict__ dec_emb, const float* __restrict__ Wih,
        const float* __restrict__ Whh, const float* __restrict__ bih,
        const float* __restrict__ bhh, const int* __restrict__ tokens,
        const float* __restrict__ h_ws, float* __restrict__ gates) {
    __shared__ float e_lds[BEAM * ED];
    __shared__ float h_lds[BEAM * HD];
    int tid = threadIdx.x;
    for (int idx = tid; idx < BEAM * ED; idx += 1024) {
        int b = idx / ED, k = idx - b * ED;
        e_lds[idx] = dec_emb[(size_t)tokens[b] * ED + k];
        h_lds[idx] = h_ws[idx];
    }
    __syncthreads();
    int wv = tid >> 6, lane = tid & 63;
    int r = blockIdx.x * 16 + wv;
    const float* wi = Wih + (size_t)r * ED;
    const float* wh = Whh + (size_t)r * HD;
    float acc[BEAM];
#pragma unroll
    for (int b = 0; b < BEAM; b++) acc[b] = 0.f;
    for (int ki = 0; ki < 8; ki++) {
        int k = ki * 64 + lane;
        if (k < ED) {
            float w = wi[k];
#pragma unroll
            for (int b = 0; b < BEAM; b++) acc[b] += w * e_lds[b * ED + k];
        }
    }
    for (int ki = 0; ki < 8; ki++) {
        int k = ki * 64 + lane;
        if (k < HD) {
            float w = wh[k];
#pragma unroll
            for (int b = 0; b < BEAM; b++) acc[b] += w * h_lds[b * HD + k];
        }
    }
#pragma unroll
    for (int b = 0; b < BEAM; b++) {
        float v = acc[b];
        for (int o = 32; o; o >>= 1) v += __shfl_down(v, o);
        acc[b] = v;
    }
    if (lane == 0) {
        float bb = bih[r] + bhh[r];
#pragma unroll
        for (int b = 0; b < BEAM; b++) gates[b * G4 + r] = acc[b] + bb;
    }
}

__global__ void k_logits_f(const float* __restrict__ outW, const float* __restrict__ outB,
                           const float* __restrict__ o_ws, float* __restrict__ logits,
                           double* __restrict__ partials) {
    __shared__ float o_lds[BEAM * HD];
    __shared__ double ered[4][BEAM];
    int tid = threadIdx.x;
    for (int idx = tid; idx < BEAM * HD; idx += 256) o_lds[idx] = o_ws[idx];
    __syncthreads();
    int wv = tid >> 6, lane = tid & 63;
    int w = blockIdx.x * 4 + wv;
    double esum = 0.0;
    for (int pi = 0; pi < 16; pi++) {
        int p = w * 16 + pi;
        if (p >= PV) break;
        const float* wr = outW + (size_t)p * HD;
        float acc[BEAM];
#pragma unroll
        for (int b = 0; b < BEAM; b++) acc[b] = 0.f;
        for (int ki = 0; ki < 8; ki++) {
            int k = ki * 64 + lane;
            if (k < HD) {
                float x = wr[k];
#pragma unroll
                for (int b = 0; b < BEAM; b++) acc[b] += x * o_lds[b * HD + k];
            }
        }
#pragma unroll
        for (int b = 0; b < BEAM; b++)
            for (int o = 32; o; o >>= 1) acc[b] += __shfl_xor(acc[b], o);
        if (lane < BEAM) {
            float lg = 0.f;
#pragma unroll
            for (int b = 0; b < BEAM; b++) if (lane == b) lg = acc[b];
            lg += outB[p];
            logits[(size_t)lane * PV + p] = lg;
            esum += exp((double)lg);
        }
    }
    if (lane < BEAM) ered[wv][lane] = esum;
    __syncthreads();
    if (tid < BEAM) partials[blockIdx.x * BEAM + tid] =
        ered[0][tid] + ered[1][tid] + ered[2][tid] + ered[3][tid];
}

__global__ __launch_bounds__(256) void k_topk_row(const float* __restrict__ logits,
                                                  u64* __restrict__ cands) {
    const int CH = 1563;
    int r = blockIdx.x >> 5, ci = blockIdx.x & 31;
    int base = ci * CH;
    int tid = threadIdx.x;
    int wv = tid >> 6, lane = tid & 63;
    u64 key[7];
#pragma unroll
    for (int e = 0; e < 7; e++) {
        int p = base + e * 256 + tid;
        key[e] = 0ull;
        if (p < base + CH && p < PV) {
            float v = logits[(size_t)r * PV + p];
            key[e] = ((u64)fkey(v) << 32) | (unsigned)(~(unsigned)p);
        }
    }
    __shared__ u64 wred[4];
    __shared__ u64 winlds;
    for (int round = 0; round < BEAM; round++) {
        u64 mx = 0ull;
#pragma unroll
        for (int e = 0; e < 7; e++) if (key[e] > mx) mx = key[e];
        for (int o = 32; o; o >>= 1) {
            u64 other = __shfl_down(mx, o);
            if (other > mx) mx = other;
        }
        if (lane == 0) wred[wv] = mx;
        __syncthreads();
        if (tid == 0) {
            u64 wn = wred[0];
            for (int i = 1; i < 4; i++) if (wred[i] > wn) wn = wred[i];
            winlds = wn;
            cands[blockIdx.x * BEAM + round] = wn;
        }
        __syncthreads();
        u64 win = winlds;
#pragma unroll
        for (int e = 0; e < 7; e++) if (key[e] == win) key[e] = 0ull;
    }
}

__global__ __launch_bounds__(256) void k_merge(
        const double* __restrict__ partials, int npart,
        const u64* __restrict__ cands,
        double* __restrict__ scores, int* __restrict__ tokens,
        const float* __restrict__ h2_ws, const float* __restrict__ c2_ws,
        float* __restrict__ h_ws, float* __restrict__ c_ws,
        int* __restrict__ prevKs, int* __restrict__ nextYs, int t) {
    __shared__ double wredd[4];
    __shared__ double lse_lds[BEAM];
    __shared__ double sc_lds[BEAM];
    __shared__ double bwv[4];
    __shared__ unsigned bwf[4];
    __shared__ unsigned winf_s;
    __shared__ int pk_lds[BEAM];
    __shared__ int ny_lds[BEAM];
    __shared__ double val_lds[BEAM];
    int tid = threadIdx.x;
    int wv = tid >> 6, lane = tid & 63;
    if (tid < BEAM) sc_lds[tid] = scores[tid];
    for (int b = 0; b < BEAM; b++) {
        double s = 0.0;
        for (int j = tid; j < npart; j += 256) s += partials[j * BEAM + b];
        for (int o = 32; o; o >>= 1) s += __shfl_down(s, o);
        if (lane == 0) wredd[wv] = s;
        __syncthreads();
        if (tid == 0) lse_lds[b] = log(wredd[0] + wredd[1] + wredd[2] + wredd[3]);
        __syncthreads();
    }
    double   cv[13];
    unsigned cf[13];
#pragma unroll
    for (int e = 0; e < 13; e++) {
        int c = e * 256 + tid;
        cv[e] = -1.0e308; cf[e] = 0xFFFFFFFFu;
        if (c < 3200) {
            u64 k0 = cands[c];
            if (k0) {
                int r = c / 320;
                float v = unfkey((unsigned)(k0 >> 32));
                unsigned p = ~((unsigned)k0);
                double v2;
                if (t == 0) v2 = (r == 0) ? ((double)v - lse_lds[0]) : (double)NEGF;
                else        v2 = ((double)v - lse_lds[r]) + sc_lds[r];
                cv[e] = v2;
                cf[e] = (unsigned)r * PV + p;
            }
        }
    }
    for (int round = 0; round < BEAM; round++) {
        double bv = -1.0e308; unsigned bf = 0xFFFFFFFFu;
#pragma unroll
        for (int e = 0; e < 13; e++) {
            if (cv[e] > bv || (cv[e] == bv && cf[e] < bf)) { bv = cv[e]; bf = cf[e]; }
        }
        for (int o = 32; o; o >>= 1) {
            double ov = __shfl_down(bv, o);
            unsigned of = __shfl_down(bf, o);
            if (ov > bv || (ov == bv && of < bf)) { bv = ov; bf = of; }
        }
        if (lane == 0) { bwv[wv] = bv; bwf[wv] = bf; }
        __syncthreads();
        if (tid == 0) {
            double xv = bwv[0]; unsigned xf = bwf[0];
            for (int i = 1; i < 4; i++) {
                if (bwv[i] > xv || (bwv[i] == xv && bwf[i] < xf)) { xv = bwv[i]; xf = bwf[i]; }
            }
            winf_s = xf;
            int pk = (int)(xf / PV);
            int ny = (int)(xf - (unsigned)pk * PV);
            pk_lds[round] = pk; ny_lds[round] = ny; val_lds[round] = xv;
        }
        __syncthreads();
        unsigned wff = winf_s;
#pragma unroll
        for (int e = 0; e < 13; e++) {
            if (cf[e] == wff) { cv[e] = -1.0e308; cf[e] = 0xFFFFFFFFu; }
        }
    }
    if (tid < BEAM) {
        scores[tid] = val_lds[tid];
        tokens[tid] = ny_lds[tid];
        prevKs[t * BEAM + tid] = pk_lds[tid];
        nextYs[t * BEAM + tid] = ny_lds[tid];
    }
    __syncthreads();
    for (int idx = tid; idx < BEAM * HD; idx += 256) {
        int i = idx / HD, j = idx - i * HD;
        h_ws[idx] = h2_ws[pk_lds[i] * HD + j];
        c_ws[idx] = c2_ws[pk_lds[i] * HD + j];
    }
}

__global__ void k_traceback(const int* __restrict__ prevKs, const int* __restrict__ nextYs,
                            int* __restrict__ out) {
    int k = threadIdx.x;
    if (k >= BEAM) return;
    int cur = k;
    for (int t = MAXLEN - 1; t >= 0; t--) {
        out[k * MAXLEN + t] = nextYs[t * BEAM + cur];
        cur = prevKs[t * BEAM + cur];
    }
}

extern "C" void kernel_launch(void* const* d_in, const int* in_sizes, int n_in,
                              void* d_out, int out_size, void* d_ws, size_t ws_size,
                              hipStream_t stream) {
    const int*   g_seq  = (const int*)  d_in[0];
    const float* encEmb = (const float*)d_in[1];
    const float* encWih = (const float*)d_in[2];
    const float* encWhh = (const float*)d_in[3];
    const float* encBih = (const float*)d_in[4];
    const float* encBhh = (const float*)d_in[5];
    const float* decEmb = (const float*)d_in[6];
    const float* decWih = (const float*)d_in[7];
    const float* decWhh = (const float*)d_in[8];
    const float* decBih = (const float*)d_in[9];
    const float* decBhh = (const float*)d_in[10];
    const float* attnW  = (const float*)d_in[11];
    const float* outW   = (const float*)d_in[12];
    const float* outB   = (const float*)d_in[13];

    float* ws = (float*)d_ws;
    float*  X     = ws + OFF_X;
    float*  cbuf  = ws + OFF_CBUF;
    float*  gbuf  = ws + OFF_GBUF;
    float*  ctx   = ws + OFF_CTX;
    float*  dh    = ws + OFF_DH;
    float*  dc    = ws + OFF_DC;
    float*  dg    = ws + OFF_DG;
    float*  h2    = ws + OFF_H2;
    float*  c2    = ws + OFF_C2;
    float*  o     = ws + OFF_O;
    double* scb   = (double*)(ws + OFF_SCD);   // ping-pong pair of 10 doubles
    int*    tok   = (int*)(ws + OFF_TOK);
    int*    prevK = (int*)(ws + OFF_PREVK);
    int*    nextY = (int*)(ws + OFF_NEXTY);
    float*  outW4 = ws + OFF_OWT;

    bool bigws = (ws_size >= NEED_T_BYTES);

    k_prep<<<16000, 256, 0, stream>>>(g_seq, encEmb, encWih, encBih, encBhh, X, cbuf);
    if (bigws) k_transpose4<<<dim3(782, 8), 256, 0, stream>>>(outW, outW4);

    for (int t = 0; t <= SLEN; t++)
        k_enc<<<250, 256, 0, stream>>>(encWhh, X, gbuf, cbuf, ctx, dh, dc, scb, tok, t);

    if (bigws) {
        double* part = (double*)(ws + OFF_PARTD);
        u64*    cand = (u64*)(ws + OFF_CAND);
        for (int t = 0; t < MAXLEN; t++) {
            int m = t - 1;
            const double* sin = scb + ((m & 1) ? 10 : 0);
            double*       sout = scb + (((m + 1) & 1) ? 10 : 0);
            if (t == 0) { sin = scb; sout = scb + 10; }   // unused at t==0
            k_gates_m<<<125, 512, 0, stream>>>(decEmb, decWih, decWhh, decBih, decBhh,
                                               part, cand, sin, sout,
                                               h2, c2, dc, dh, prevK, nextY, dg, t);
            k_attn_oproj<<<125, 256, 0, stream>>>(dg, dc, ctx, attnW, h2, c2, o);
            k_logits_topk<<<NSTRIP, 1024, 0, stream>>>(outW4, outB, o, cand, part);
        }
        int mf = MAXLEN - 1;
        k_final<<<1, 512, 0, stream>>>(part, cand, scb + ((mf & 1) ? 10 : 0),
                                       prevK, nextY, (int*)d_out);
    } else {
        // R4-validated fallback (row-major out_W)
        double* part  = (double*)(ws + OFF_PARTF);
        u64*    cand  = (u64*)(ws + OFF_CANDF);
        float*  logits = ws + OFF_LOG;
        const int npart = 782;
        for (int t = 0; t < MAXLEN; t++) {
            k_gates<<<125, 1024, 0, stream>>>(decEmb, decWih, decWhh, decBih, decBhh, tok, dh, dg);
            k_attn_oproj<<<125, 256, 0, stream>>>(dg, dc, ctx, attnW, h2, c2, o);
            k_logits_f<<<782, 256, 0, stream>>>(outW, outB, o, logits, part);
            k_topk_row<<<320, 256, 0, stream>>>(logits, cand);
            k_merge<<<1, 256, 0, stream>>>(part, npart, cand, scb, tok, h2, c2, dh, dc, prevK, nextY, t);
        }
        k_traceback<<<1, 64, 0, stream>>>(prevK, nextY, (int*)d_out);
    }
}